// Round 9
// baseline (393.516 us; speedup 1.0000x reference)
//
#include <hip/hip_runtime.h>
#include <hip/hip_bf16.h>
#include <cstdint>

// ---------------------------------------------------------------------------
// GAT 2-layer model on MI355X.
// R14-R16: spmm gather loop pinned at ~42us by the random-gather L2-miss
//   path (~2.75 TB/s invariant). Hot loop FROZEN.
// R17 (WIN 290.6->279.1): GEMMs on bf16 MFMA via LDS staging, split
//   precision (hi@hi+hi@lo+lo@hi).
// R18 (REGR): device-wide scatter CSR -> write-amplification. Lesson:
//   scatter must stay window-confined (L2-resident bins).
// R19 (REGR): LDS-free gemm regressed; barrier-paced staging is load-bearing.
// R20 (WIN 279.1->268.4): fused setup kernel (9 launches), finalize@512t.
// R21: (a) BIN_SHIFT 8->7: 782 bins -> finalize passes 2x more parallel.
//   (b) post_pool fused into spmm<0> epilogue WITHOUT LDS: bias+ELU
//   in-register, 4-node wave butterfly when batch-uniform, 64 atomics/wave
//   to the 64KB pool table. Deletes accbuf (51.2MB traffic) + a launch.
// R22: identical resubmission of R21 — round 8 failed on container
//   infrastructure ("MI355X container failed twice"), not on the kernel;
//   no measurement was produced. Audit found no crash path in the diff.
// ---------------------------------------------------------------------------

#define BIN_SHIFT 7
#define BIN_NODES 128
#define BIN_CAP 3584
#define PLACE_CHUNK 2048

typedef __attribute__((ext_vector_type(8))) short bf16x8;
typedef __attribute__((ext_vector_type(4))) float f32x4;

__device__ __forceinline__ float wave_reduce_sum(float v) {
#pragma unroll
  for (int off = 32; off > 0; off >>= 1) v += __shfl_xor(v, off, 64);
  return v;
}

__device__ __forceinline__ unsigned short f2bf(float f) {  // RNE
  unsigned int u = __float_as_uint(f);
  u += 0x7fffu + ((u >> 16) & 1u);
  return (unsigned short)(u >> 16);
}
__device__ __forceinline__ float bf2f(unsigned short u) {
  return __uint_as_float(((unsigned int)u) << 16);
}

// ---------------- fused setup: memsets + bounds + weight presplit ----------

// Grid layout (256 threads/block):
//   [0,32)    wsplit W1 (128x64)
//   [32,48)   wsplit W2 (64x64)
//   [48,50)   bounds (gstart, G+1=257 entries)
//   [50,54)   zero binCursor (NB=782)
//   [54,118)  zero pool (G*64 = 16384 floats)
__global__ __launch_bounds__(256) void setup_kernel(
    const float* __restrict__ W1, unsigned short* __restrict__ w1thi,
    unsigned short* __restrict__ w1tlo, const float* __restrict__ W2,
    unsigned short* __restrict__ w2thi, unsigned short* __restrict__ w2tlo,
    const int* __restrict__ batch, int* __restrict__ gstart,
    int* __restrict__ binCursor, float* __restrict__ pool, int N, int G, int NB) {
  const int b = blockIdx.x;
  const int t = threadIdx.x;
  if (b < 32) {
    int idx = b * 256 + t;  // < 8192 = 128*64
    int n = idx & 63, k = idx >> 6;
    float v = W1[(size_t)k * 64 + n];
    unsigned short h = f2bf(v);
    w1thi[(size_t)n * 128 + k] = h;
    w1tlo[(size_t)n * 128 + k] = f2bf(v - bf2f(h));
  } else if (b < 48) {
    int idx = (b - 32) * 256 + t;  // < 4096 = 64*64
    int n = idx & 63, k = idx >> 6;
    float v = W2[(size_t)k * 64 + n];
    unsigned short h = f2bf(v);
    w2thi[(size_t)n * 64 + k] = h;
    w2tlo[(size_t)n * 64 + k] = f2bf(v - bf2f(h));
  } else if (b < 50) {
    int g = (b - 48) * 256 + t;
    if (g <= G) {
      int lo = 0, hi = N;
      while (lo < hi) {
        int mid = (lo + hi) >> 1;
        if (batch[mid] < g) lo = mid + 1;
        else hi = mid;
      }
      gstart[g] = lo;
    }
  } else if (b < 54) {
    int i = (b - 50) * 256 + t;
    if (i < NB) binCursor[i] = 0;
  } else {
    int i = (b - 54) * 256 + t;  // < 16384
    pool[i] = 0.f;
  }
}

// ---------------- CSR build (capacity-binned, single ei pass) ----------------

__global__ __launch_bounds__(256) void bin_place_kernel(
    const int* __restrict__ ei, int E, int M, int NB,
    int* __restrict__ binCursor, unsigned int* __restrict__ binned) {
  __shared__ int cur[1024];
  __shared__ int res[1024];
  const int t = threadIdx.x;
  const int cbase = blockIdx.x * PLACE_CHUNK;

  for (int i = t; i < NB; i += 256) cur[i] = 0;
  __syncthreads();

  unsigned int pk[PLACE_CHUNK / 256];
  int br[PLACE_CHUNK / 256];
#pragma unroll
  for (int j = 0; j < PLACE_CHUNK / 256; ++j) {
    int i = cbase + t + j * 256;
    if (i < M) {
      int s, d;
      if (i < E) { s = ei[i]; d = ei[E + i]; } else { s = d = i - E; }
      int b = d >> BIN_SHIFT;
      int r = atomicAdd(&cur[b], 1);
      pk[j] = ((unsigned int)(d & (BIN_NODES - 1)) << 24) | (unsigned int)s;
      br[j] = (b << 16) | r;  // b<1024 (15b), r<2048 (16b)
    } else {
      br[j] = -1;
    }
  }
  __syncthreads();
  for (int i = t; i < NB; i += 256) {
    int c = cur[i];
    res[i] = c ? atomicAdd(&binCursor[i], c) : 0;
  }
  __syncthreads();
#pragma unroll
  for (int j = 0; j < PLACE_CHUNK / 256; ++j) {
    if (br[j] >= 0) {
      int b = br[j] >> 16;
      int pos = res[b] + (br[j] & 0xFFFF);
      if (pos < BIN_CAP) binned[(size_t)b * BIN_CAP + pos] = pk[j];
    }
  }
}

// One 128-node bin per block, 512 threads: both edge passes ~4.3 iterations.
__global__ __launch_bounds__(512) void csr_finalize_kernel(
    const unsigned int* __restrict__ binned, const int* __restrict__ binCursor,
    int* __restrict__ rowbeg, int* __restrict__ rowend, int* __restrict__ csrc,
    int N, int NB) {
  __shared__ int cnt[128];
  __shared__ int wsum[2];
  const int b = blockIdx.x;
  const int t = threadIdx.x;
  const int nodeBase = b << BIN_SHIFT;
  const int eBase = b * BIN_CAP;
  const int cntE = binCursor[b];

  if (t < 128) cnt[t] = 0;
  __syncthreads();
  for (int i = t; i < cntE; i += 512) {
    atomicAdd(&cnt[binned[eBase + i] >> 24], 1);
  }
  __syncthreads();
  const int lane = t & 63, wv = t >> 6;
  int v = (t < 128) ? cnt[t] : 0;
  int x = v;
#pragma unroll
  for (int o = 1; o < 64; o <<= 1) {
    int u = __shfl_up(x, o, 64);
    if (lane >= o) x += u;
  }
  if (t < 128 && lane == 63) wsum[wv] = x;
  __syncthreads();
  if (t < 128) {
    const int o = ((wv == 1) ? wsum[0] : 0) + x - v;
    int node = nodeBase + t;
    if (node < N) {
      rowbeg[node] = eBase + o;
      rowend[node] = eBase + o + v;
    }
    cnt[t] = o;  // reuse as cursor
  }
  __syncthreads();
  for (int i = t; i < cntE; i += 512) {
    unsigned int pk = binned[eBase + i];
    int r = atomicAdd(&cnt[pk >> 24], 1);
    csrc[eBase + r] = (int)(pk & 0xFFFFFFu);
  }
}

// ---------------- dense compute ----------------

// hb[N][64] (bf16) = A[N][KDIM] @ W[KDIM][64] via split-bf16 MFMA.
// R17 form (proven): LDS-staged A (split on the fly) + pre-split W^T,
// barrier-paced; fused al epilogue from exact fp32 accumulators.
template <int KDIM>
__global__ __launch_bounds__(256) void gemm_mfma(
    const float* __restrict__ A, const unsigned short* __restrict__ Wt_hi,
    const unsigned short* __restrict__ Wt_lo, unsigned short* __restrict__ hb,
    const float* __restrict__ a_src, const float* __restrict__ a_dst,
    float* __restrict__ alsrc, float* __restrict__ aldst, int N) {
  __shared__ unsigned short Ah[64][40], Al[64][40], Bh[64][40], Bl[64][40];
  const int block_m = blockIdx.x * 64;
  const int t = threadIdx.x;
  const int lane = t & 63;
  const int m0 = (t >> 6) * 16;  // wave's row base
  const int lc = lane & 15;      // frag col / A row
  const int lr = lane >> 4;      // k-group / C row-group
  const int srow = t >> 2;            // staging: row (0..63)
  const int skslot = (t & 3) * 8;     // staging: k slot (0,8,16,24)

  f32x4 acc[4] = {};

  for (int kc = 0; kc < KDIM; kc += 32) {
    // ---- stage A chunk (split fp32 -> bf16 hi/lo) ----
    {
      int gn = block_m + srow;
      if (gn >= N) gn = N - 1;
      const float4 v0 = *(const float4*)(A + (size_t)gn * KDIM + kc + skslot);
      const float4 v1 = *(const float4*)(A + (size_t)gn * KDIM + kc + skslot + 4);
      float v[8] = {v0.x, v0.y, v0.z, v0.w, v1.x, v1.y, v1.z, v1.w};
      unsigned short h8[8], l8[8];
#pragma unroll
      for (int j = 0; j < 8; ++j) {
        h8[j] = f2bf(v[j]);
        l8[j] = f2bf(v[j] - bf2f(h8[j]));
      }
      *(uint4*)&Ah[srow][skslot] = *(const uint4*)h8;
      *(uint4*)&Al[srow][skslot] = *(const uint4*)l8;
    }
    // ---- stage W chunk (pre-split, transposed [n][k]) ----
    {
      const uint4 wh = *(const uint4*)(Wt_hi + (size_t)srow * KDIM + kc + skslot);
      const uint4 wl = *(const uint4*)(Wt_lo + (size_t)srow * KDIM + kc + skslot);
      *(uint4*)&Bh[srow][skslot] = wh;
      *(uint4*)&Bl[srow][skslot] = wl;
    }
    __syncthreads();

    const bf16x8 ah = *(const bf16x8*)&Ah[m0 + lc][lr * 8];
    const bf16x8 al = *(const bf16x8*)&Al[m0 + lc][lr * 8];
#pragma unroll
    for (int nf = 0; nf < 4; ++nf) {
      const bf16x8 bh = *(const bf16x8*)&Bh[nf * 16 + lc][lr * 8];
      const bf16x8 bl = *(const bf16x8*)&Bl[nf * 16 + lc][lr * 8];
      acc[nf] = __builtin_amdgcn_mfma_f32_16x16x32_bf16(ah, bh, acc[nf], 0, 0, 0);
      acc[nf] = __builtin_amdgcn_mfma_f32_16x16x32_bf16(ah, bl, acc[nf], 0, 0, 0);
      acc[nf] = __builtin_amdgcn_mfma_f32_16x16x32_bf16(al, bh, acc[nf], 0, 0, 0);
    }
    __syncthreads();
  }

  // ---- epilogue: hb (bf16) + al reductions from fp32 acc ----
  // D[row = m0 + lr*4 + r][col = nf*16 + lc] = acc[nf][r]
  float as4[4], ad4[4];
#pragma unroll
  for (int nf = 0; nf < 4; ++nf) {
    as4[nf] = a_src[nf * 16 + lc];
    ad4[nf] = a_dst[nf * 16 + lc];
  }
#pragma unroll
  for (int r = 0; r < 4; ++r) {
    const int gn = block_m + m0 + lr * 4 + r;
    float ps = 0.f, pd = 0.f;
#pragma unroll
    for (int nf = 0; nf < 4; ++nf) {
      const float v = acc[nf][r];
      if (gn < N) hb[(size_t)gn * 64 + nf * 16 + lc] = f2bf(v);
      ps += v * as4[nf];
      pd += v * ad4[nf];
    }
#pragma unroll
    for (int off = 1; off < 16; off <<= 1) {
      ps += __shfl_xor(ps, off, 64);
      pd += __shfl_xor(pd, off, 64);
    }
    if (lc == 0 && gn < N) {
      alsrc[gn] = ps;
      aldst[gn] = pd;
    }
  }
}

// Fused no-max softmax + spmm (R16 hot loop, frozen).
// MODE 1: bias+ELU+store to outbuf (layer 1 -> h1e).
// MODE 0: bias+ELU+mean-pool accumulation (layer 2): 4-node wave butterfly
//   when batch-uniform (common: ~390 nodes/graph, sorted), then 64 atomics
//   per wave into the 64KB pool table. No LDS, no extra sync. Requires
//   N%16==0 (N=100000) so all lanes are active for the shuffles.
template <int MODE>
__global__ __launch_bounds__(256) void spmm_fused_kernel(
    const int* __restrict__ rowbeg, const int* __restrict__ rowend,
    const int* __restrict__ csrc,
    const float* __restrict__ alsrc, const float* __restrict__ aldst,
    const unsigned short* __restrict__ hb, const float* __restrict__ bias,
    float* __restrict__ outbuf, const int* __restrict__ batch,
    float* __restrict__ pool, int N) {
  const int t = threadIdx.x;
  const int l = t & 15;        // slot within group
  const int gb = t & 48;       // group base lane within wave
  const int half = l >> 3;     // which edge of the pair this lane serves
  const int f0 = (l & 7) * 8;  // first feature owned by this lane
  const int node = blockIdx.x * 16 + (t >> 4);
  if (node >= N) return;
  const int start = rowbeg[node];
  const int end = rowend[node];
  const float ad = aldst[node];

  float ssum = 0.f;
  float acc[8] = {};

  int i0 = start + l;
  bool v0 = i0 < end;
  int s = v0 ? csrc[i0] : 0;
  float w;
  {
    float e = alsrc[s] + ad;
    e = (e > 0.f) ? e : 0.2f * e;  // leaky_relu 0.2
    w = v0 ? __expf(fminf(e, 80.f)) : 0.f;
  }

  for (int base = start; base < end; base += 16) {
    int in = base + 16 + l;
    bool vn = in < end;
    int sn = vn ? csrc[in] : 0;
    float aln = alsrc[sn];

    uint4 u[8];
#pragma unroll
    for (int j = 0; j < 8; ++j) {
      int sj = __shfl(s, gb + 2 * j + half, 64);
      u[j] = *(const uint4*)(hb + (size_t)sj * 64 + f0);
    }

    ssum += w;
#pragma unroll
    for (int j = 0; j < 8; ++j) {
      float wj = __shfl(w, gb + 2 * j + half, 64);
      acc[0] += wj * __uint_as_float(u[j].x << 16);
      acc[1] += wj * __uint_as_float(u[j].x & 0xFFFF0000u);
      acc[2] += wj * __uint_as_float(u[j].y << 16);
      acc[3] += wj * __uint_as_float(u[j].y & 0xFFFF0000u);
      acc[4] += wj * __uint_as_float(u[j].z << 16);
      acc[5] += wj * __uint_as_float(u[j].z & 0xFFFF0000u);
      acc[6] += wj * __uint_as_float(u[j].w << 16);
      acc[7] += wj * __uint_as_float(u[j].w & 0xFFFF0000u);
    }

    float en = aln + ad;
    en = (en > 0.f) ? en : 0.2f * en;
    w = vn ? __expf(fminf(en, 80.f)) : 0.f;
    s = sn;
  }

#pragma unroll
  for (int k = 0; k < 8; ++k) acc[k] += __shfl_xor(acc[k], 8, 64);
#pragma unroll
  for (int off = 1; off < 16; off <<= 1) ssum += __shfl_xor(ssum, off, 64);

  // Both halves of each lane-pair now hold identical acc/ssum.
  const float inv = 1.0f / ssum;  // >= 1 edge (self-loop)
  float r[8];
#pragma unroll
  for (int k = 0; k < 8; ++k) r[k] = acc[k] * inv;
  {
    const float4 b40 = *(const float4*)(bias + f0);
    const float4 b41 = *(const float4*)(bias + f0 + 4);
    r[0] += b40.x; r[1] += b40.y; r[2] += b40.z; r[3] += b40.w;
    r[4] += b41.x; r[5] += b41.y; r[6] += b41.z; r[7] += b41.w;
#pragma unroll
    for (int k = 0; k < 8; ++k) r[k] = (r[k] > 0.f) ? r[k] : expm1f(r[k]);
  }

  if (MODE == 1) {
    if (half == 0) {
      *(float4*)(outbuf + (size_t)node * 64 + f0) = make_float4(r[0], r[1], r[2], r[3]);
      *(float4*)(outbuf + (size_t)node * 64 + f0 + 4) = make_float4(r[4], r[5], r[6], r[7]);
    }
  } else {
    const int g = batch[node];
    const bool uni = __all(g == __shfl_xor(g, 16, 64)) &&
                     __all(g == __shfl_xor(g, 32, 64));
    if (uni) {
#pragma unroll
      for (int k = 0; k < 8; ++k) {
        r[k] += __shfl_xor(r[k], 16, 64);
        r[k] += __shfl_xor(r[k], 32, 64);
      }
      if ((t & 63) < 8) {
#pragma unroll
        for (int k = 0; k < 8; ++k)
          atomicAdd(&pool[(size_t)g * 64 + f0 + k], r[k]);
      }
    } else {
      if (half == 0) {
#pragma unroll
        for (int k = 0; k < 8; ++k)
          atomicAdd(&pool[(size_t)g * 64 + f0 + k], r[k]);
      }
    }
  }
}

// out[g] = (pool[g,:]/cnt[g]) . Wfc + bfc ; cnt from sorted-batch bounds.
__global__ void final_kernel(const float* __restrict__ pool, const int* __restrict__ gstart,
                             const float* __restrict__ Wfc, const float* __restrict__ bfc,
                             float* __restrict__ out, int G) {
  int wid = (blockIdx.x * blockDim.x + threadIdx.x) >> 6;
  int lane = threadIdx.x & 63;
  if (wid >= G) return;
  float c = (float)max(gstart[wid + 1] - gstart[wid], 1);
  float v = pool[(size_t)wid * 64 + lane] * (1.0f / c) * Wfc[lane];
  v = wave_reduce_sum(v);
  if (lane == 0) out[wid] = v + bfc[0];
}

// ---------------------------------------------------------------------------

extern "C" void kernel_launch(void* const* d_in, const int* in_sizes, int n_in,
                              void* d_out, int out_size, void* d_ws, size_t ws_size,
                              hipStream_t stream) {
  const float* x     = (const float*)d_in[0];
  const int*   ei    = (const int*)d_in[1];
  const int*   batch = (const int*)d_in[2];
  const float* W1    = (const float*)d_in[3];
  const float* asrc1 = (const float*)d_in[4];
  const float* adst1 = (const float*)d_in[5];
  const float* b1    = (const float*)d_in[6];
  const float* W2    = (const float*)d_in[7];
  const float* asrc2 = (const float*)d_in[8];
  const float* adst2 = (const float*)d_in[9];
  const float* b2    = (const float*)d_in[10];
  const float* Wfc   = (const float*)d_in[11];
  const float* bfc   = (const float*)d_in[12];
  float* out = (float*)d_out;

  const int N = in_sizes[0] / 128;  // 100000
  const int E = in_sizes[1] / 2;    // 1600000
  const int G = 256;
  const int M = E + N;              // edges incl self-loops
  const int NB = (N + BIN_NODES - 1) >> BIN_SHIFT;  // 782 bins

  // workspace carve (256B aligned)
  char* p = (char*)d_ws;
  auto alloc = [&](size_t bytes) {
    char* r = p;
    p += (bytes + 255) & ~size_t(255);
    return r;
  };
  float*          h1e    = (float*)alloc((size_t)N * 64 * 4);
  unsigned short* hb     = (unsigned short*)alloc((size_t)N * 64 * 2);
  float* alsrc  = (float*)alloc((size_t)N * 4);
  float* aldst  = (float*)alloc((size_t)N * 4);
  int*   rowbeg = (int*)alloc((size_t)N * 4);
  int*   rowend = (int*)alloc((size_t)N * 4);
  int*   csrc   = (int*)alloc((size_t)NB * BIN_CAP * 4);
  unsigned int* binned = (unsigned int*)alloc((size_t)NB * BIN_CAP * 4);
  int*   binCursor = (int*)alloc((size_t)NB * 4);
  float* pool   = (float*)alloc((size_t)G * 64 * 4);
  int*   gstart = (int*)alloc((size_t)(G + 1) * 4);
  unsigned short* w1thi = (unsigned short*)alloc((size_t)64 * 128 * 2);
  unsigned short* w1tlo = (unsigned short*)alloc((size_t)64 * 128 * 2);
  unsigned short* w2thi = (unsigned short*)alloc((size_t)64 * 64 * 2);
  unsigned short* w2tlo = (unsigned short*)alloc((size_t)64 * 64 * 2);

  // ---- fused setup + CSR build ----
  setup_kernel<<<118, 256, 0, stream>>>(W1, w1thi, w1tlo, W2, w2thi, w2tlo,
                                        batch, gstart, binCursor, pool, N, G, NB);
  bin_place_kernel<<<(M + PLACE_CHUNK - 1) / PLACE_CHUNK, 256, 0, stream>>>(
      ei, E, M, NB, binCursor, binned);
  csr_finalize_kernel<<<NB, 512, 0, stream>>>(binned, binCursor, rowbeg, rowend,
                                              csrc, N, NB);

  // ---- layer 1 ----
  gemm_mfma<128><<<(N + 63) / 64, 256, 0, stream>>>(x, w1thi, w1tlo, hb, asrc1, adst1,
                                                    alsrc, aldst, N);
  spmm_fused_kernel<1><<<(N + 15) / 16, 256, 0, stream>>>(
      rowbeg, rowend, csrc, alsrc, aldst, hb, b1, h1e, nullptr, nullptr, N);

  // ---- layer 2 (pool fused into spmm epilogue) ----
  gemm_mfma<64><<<(N + 63) / 64, 256, 0, stream>>>(h1e, w2thi, w2tlo, hb, asrc2, adst2,
                                                   alsrc, aldst, N);
  spmm_fused_kernel<0><<<(N + 15) / 16, 256, 0, stream>>>(
      rowbeg, rowend, csrc, alsrc, aldst, hb, b2, nullptr, batch, pool, N);

  // ---- readout ----
  final_kernel<<<(G * 64 + 255) / 256, 256, 0, stream>>>(pool, gstart, Wfc, bfc, out, G);
}

// Round 10
// 269.554 us; speedup vs baseline: 1.4599x; 1.4599x over previous
//
#include <hip/hip_runtime.h>
#include <hip/hip_bf16.h>
#include <cstdint>

// ---------------------------------------------------------------------------
// GAT 2-layer model on MI355X.
// R14-R16: spmm gather loop pinned at ~42us by the random-gather L2-miss
//   path (~2.75 TB/s invariant). Hot loop FROZEN.
// R17 (WIN 290.6->279.1): GEMMs on bf16 MFMA via LDS staging, split
//   precision (hi@hi+hi@lo+lo@hi).
// R18 (REGR): device-wide scatter CSR -> write-amplification. Lesson:
//   scatter must stay window-confined (L2-resident bins).
// R19 (REGR): LDS-free gemm regressed; barrier-paced staging is load-bearing.
// R20 (WIN 279.1->268.4): fused setup kernel, finalize@512t.
// R21/R22 (REGR 268->394): pool fused into spmm<0> epilogue -> 1.6M
//   device-scope atomics (25K waves x 64) to a 64KB table: 51MB HBM write
//   traffic (32B/atomic granule), spmm<0> 42->178us. Lesson: NEVER issue
//   fine-grained device-wide atomics without block-level pre-reduction;
//   post_pool's LDS pre-reduce (400K atomics, separate kernel) is the
//   right structure. Fusion fully reverted.
// R23: R20 structure + the safe R21 piece only: BIN_SHIFT 8->7 (782 bins,
//   finalize 2x more parallel, windows still L2-confined). Clean A/B of
//   BIN_SHIFT against R20's 268.4.
// ---------------------------------------------------------------------------

#define BIN_SHIFT 7
#define BIN_NODES 128
#define BIN_CAP 3584
#define PLACE_CHUNK 2048

typedef __attribute__((ext_vector_type(8))) short bf16x8;
typedef __attribute__((ext_vector_type(4))) float f32x4;

__device__ __forceinline__ float wave_reduce_sum(float v) {
#pragma unroll
  for (int off = 32; off > 0; off >>= 1) v += __shfl_xor(v, off, 64);
  return v;
}

__device__ __forceinline__ unsigned short f2bf(float f) {  // RNE
  unsigned int u = __float_as_uint(f);
  u += 0x7fffu + ((u >> 16) & 1u);
  return (unsigned short)(u >> 16);
}
__device__ __forceinline__ float bf2f(unsigned short u) {
  return __uint_as_float(((unsigned int)u) << 16);
}

// ---------------- fused setup: memsets + bounds + weight presplit ----------

// Grid layout (256 threads/block):
//   [0,32)    wsplit W1 (128x64)
//   [32,48)   wsplit W2 (64x64)
//   [48,50)   bounds (gstart, G+1=257 entries)
//   [50,54)   zero binCursor (NB=782)
//   [54,118)  zero pool (G*64 = 16384 floats)
__global__ __launch_bounds__(256) void setup_kernel(
    const float* __restrict__ W1, unsigned short* __restrict__ w1thi,
    unsigned short* __restrict__ w1tlo, const float* __restrict__ W2,
    unsigned short* __restrict__ w2thi, unsigned short* __restrict__ w2tlo,
    const int* __restrict__ batch, int* __restrict__ gstart,
    int* __restrict__ binCursor, float* __restrict__ pool, int N, int G, int NB) {
  const int b = blockIdx.x;
  const int t = threadIdx.x;
  if (b < 32) {
    int idx = b * 256 + t;  // < 8192 = 128*64
    int n = idx & 63, k = idx >> 6;
    float v = W1[(size_t)k * 64 + n];
    unsigned short h = f2bf(v);
    w1thi[(size_t)n * 128 + k] = h;
    w1tlo[(size_t)n * 128 + k] = f2bf(v - bf2f(h));
  } else if (b < 48) {
    int idx = (b - 32) * 256 + t;  // < 4096 = 64*64
    int n = idx & 63, k = idx >> 6;
    float v = W2[(size_t)k * 64 + n];
    unsigned short h = f2bf(v);
    w2thi[(size_t)n * 64 + k] = h;
    w2tlo[(size_t)n * 64 + k] = f2bf(v - bf2f(h));
  } else if (b < 50) {
    int g = (b - 48) * 256 + t;
    if (g <= G) {
      int lo = 0, hi = N;
      while (lo < hi) {
        int mid = (lo + hi) >> 1;
        if (batch[mid] < g) lo = mid + 1;
        else hi = mid;
      }
      gstart[g] = lo;
    }
  } else if (b < 54) {
    int i = (b - 50) * 256 + t;
    if (i < NB) binCursor[i] = 0;
  } else {
    int i = (b - 54) * 256 + t;  // < 16384
    pool[i] = 0.f;
  }
}

// ---------------- CSR build (capacity-binned, single ei pass) ----------------

__global__ __launch_bounds__(256) void bin_place_kernel(
    const int* __restrict__ ei, int E, int M, int NB,
    int* __restrict__ binCursor, unsigned int* __restrict__ binned) {
  __shared__ int cur[1024];
  __shared__ int res[1024];
  const int t = threadIdx.x;
  const int cbase = blockIdx.x * PLACE_CHUNK;

  for (int i = t; i < NB; i += 256) cur[i] = 0;
  __syncthreads();

  unsigned int pk[PLACE_CHUNK / 256];
  int br[PLACE_CHUNK / 256];
#pragma unroll
  for (int j = 0; j < PLACE_CHUNK / 256; ++j) {
    int i = cbase + t + j * 256;
    if (i < M) {
      int s, d;
      if (i < E) { s = ei[i]; d = ei[E + i]; } else { s = d = i - E; }
      int b = d >> BIN_SHIFT;
      int r = atomicAdd(&cur[b], 1);
      pk[j] = ((unsigned int)(d & (BIN_NODES - 1)) << 24) | (unsigned int)s;
      br[j] = (b << 16) | r;  // b<1024 (15b), r<2048 (16b)
    } else {
      br[j] = -1;
    }
  }
  __syncthreads();
  for (int i = t; i < NB; i += 256) {
    int c = cur[i];
    res[i] = c ? atomicAdd(&binCursor[i], c) : 0;
  }
  __syncthreads();
#pragma unroll
  for (int j = 0; j < PLACE_CHUNK / 256; ++j) {
    if (br[j] >= 0) {
      int b = br[j] >> 16;
      int pos = res[b] + (br[j] & 0xFFFF);
      if (pos < BIN_CAP) binned[(size_t)b * BIN_CAP + pos] = pk[j];
    }
  }
}

// One 128-node bin per block, 512 threads: both edge passes ~4.3 iterations.
__global__ __launch_bounds__(512) void csr_finalize_kernel(
    const unsigned int* __restrict__ binned, const int* __restrict__ binCursor,
    int* __restrict__ rowbeg, int* __restrict__ rowend, int* __restrict__ csrc,
    int N, int NB) {
  __shared__ int cnt[128];
  __shared__ int wsum[2];
  const int b = blockIdx.x;
  const int t = threadIdx.x;
  const int nodeBase = b << BIN_SHIFT;
  const int eBase = b * BIN_CAP;
  const int cntE = binCursor[b];

  if (t < 128) cnt[t] = 0;
  __syncthreads();
  for (int i = t; i < cntE; i += 512) {
    atomicAdd(&cnt[binned[eBase + i] >> 24], 1);
  }
  __syncthreads();
  const int lane = t & 63, wv = t >> 6;
  int v = (t < 128) ? cnt[t] : 0;
  int x = v;
#pragma unroll
  for (int o = 1; o < 64; o <<= 1) {
    int u = __shfl_up(x, o, 64);
    if (lane >= o) x += u;
  }
  if (t < 128 && lane == 63) wsum[wv] = x;
  __syncthreads();
  if (t < 128) {
    const int o = ((wv == 1) ? wsum[0] : 0) + x - v;
    int node = nodeBase + t;
    if (node < N) {
      rowbeg[node] = eBase + o;
      rowend[node] = eBase + o + v;
    }
    cnt[t] = o;  // reuse as cursor
  }
  __syncthreads();
  for (int i = t; i < cntE; i += 512) {
    unsigned int pk = binned[eBase + i];
    int r = atomicAdd(&cnt[pk >> 24], 1);
    csrc[eBase + r] = (int)(pk & 0xFFFFFFu);
  }
}

// ---------------- dense compute ----------------

// hb[N][64] (bf16) = A[N][KDIM] @ W[KDIM][64] via split-bf16 MFMA.
// R17 form (proven): LDS-staged A (split on the fly) + pre-split W^T,
// barrier-paced; fused al epilogue from exact fp32 accumulators.
template <int KDIM>
__global__ __launch_bounds__(256) void gemm_mfma(
    const float* __restrict__ A, const unsigned short* __restrict__ Wt_hi,
    const unsigned short* __restrict__ Wt_lo, unsigned short* __restrict__ hb,
    const float* __restrict__ a_src, const float* __restrict__ a_dst,
    float* __restrict__ alsrc, float* __restrict__ aldst, int N) {
  __shared__ unsigned short Ah[64][40], Al[64][40], Bh[64][40], Bl[64][40];
  const int block_m = blockIdx.x * 64;
  const int t = threadIdx.x;
  const int lane = t & 63;
  const int m0 = (t >> 6) * 16;  // wave's row base
  const int lc = lane & 15;      // frag col / A row
  const int lr = lane >> 4;      // k-group / C row-group
  const int srow = t >> 2;            // staging: row (0..63)
  const int skslot = (t & 3) * 8;     // staging: k slot (0,8,16,24)

  f32x4 acc[4] = {};

  for (int kc = 0; kc < KDIM; kc += 32) {
    // ---- stage A chunk (split fp32 -> bf16 hi/lo) ----
    {
      int gn = block_m + srow;
      if (gn >= N) gn = N - 1;
      const float4 v0 = *(const float4*)(A + (size_t)gn * KDIM + kc + skslot);
      const float4 v1 = *(const float4*)(A + (size_t)gn * KDIM + kc + skslot + 4);
      float v[8] = {v0.x, v0.y, v0.z, v0.w, v1.x, v1.y, v1.z, v1.w};
      unsigned short h8[8], l8[8];
#pragma unroll
      for (int j = 0; j < 8; ++j) {
        h8[j] = f2bf(v[j]);
        l8[j] = f2bf(v[j] - bf2f(h8[j]));
      }
      *(uint4*)&Ah[srow][skslot] = *(const uint4*)h8;
      *(uint4*)&Al[srow][skslot] = *(const uint4*)l8;
    }
    // ---- stage W chunk (pre-split, transposed [n][k]) ----
    {
      const uint4 wh = *(const uint4*)(Wt_hi + (size_t)srow * KDIM + kc + skslot);
      const uint4 wl = *(const uint4*)(Wt_lo + (size_t)srow * KDIM + kc + skslot);
      *(uint4*)&Bh[srow][skslot] = wh;
      *(uint4*)&Bl[srow][skslot] = wl;
    }
    __syncthreads();

    const bf16x8 ah = *(const bf16x8*)&Ah[m0 + lc][lr * 8];
    const bf16x8 al = *(const bf16x8*)&Al[m0 + lc][lr * 8];
#pragma unroll
    for (int nf = 0; nf < 4; ++nf) {
      const bf16x8 bh = *(const bf16x8*)&Bh[nf * 16 + lc][lr * 8];
      const bf16x8 bl = *(const bf16x8*)&Bl[nf * 16 + lc][lr * 8];
      acc[nf] = __builtin_amdgcn_mfma_f32_16x16x32_bf16(ah, bh, acc[nf], 0, 0, 0);
      acc[nf] = __builtin_amdgcn_mfma_f32_16x16x32_bf16(ah, bl, acc[nf], 0, 0, 0);
      acc[nf] = __builtin_amdgcn_mfma_f32_16x16x32_bf16(al, bh, acc[nf], 0, 0, 0);
    }
    __syncthreads();
  }

  // ---- epilogue: hb (bf16) + al reductions from fp32 acc ----
  // D[row = m0 + lr*4 + r][col = nf*16 + lc] = acc[nf][r]
  float as4[4], ad4[4];
#pragma unroll
  for (int nf = 0; nf < 4; ++nf) {
    as4[nf] = a_src[nf * 16 + lc];
    ad4[nf] = a_dst[nf * 16 + lc];
  }
#pragma unroll
  for (int r = 0; r < 4; ++r) {
    const int gn = block_m + m0 + lr * 4 + r;
    float ps = 0.f, pd = 0.f;
#pragma unroll
    for (int nf = 0; nf < 4; ++nf) {
      const float v = acc[nf][r];
      if (gn < N) hb[(size_t)gn * 64 + nf * 16 + lc] = f2bf(v);
      ps += v * as4[nf];
      pd += v * ad4[nf];
    }
#pragma unroll
    for (int off = 1; off < 16; off <<= 1) {
      ps += __shfl_xor(ps, off, 64);
      pd += __shfl_xor(pd, off, 64);
    }
    if (lc == 0 && gn < N) {
      alsrc[gn] = ps;
      aldst[gn] = pd;
    }
  }
}

// Fused no-max softmax + spmm (R16 hot loop, frozen; R20 epilogue form).
template <int ELU>
__global__ __launch_bounds__(256) void spmm_fused_kernel(
    const int* __restrict__ rowbeg, const int* __restrict__ rowend,
    const int* __restrict__ csrc,
    const float* __restrict__ alsrc, const float* __restrict__ aldst,
    const unsigned short* __restrict__ hb, const float* __restrict__ bias,
    float* __restrict__ outbuf, int N) {
  const int t = threadIdx.x;
  const int l = t & 15;        // slot within group
  const int gb = t & 48;       // group base lane within wave
  const int half = l >> 3;     // which edge of the pair this lane serves
  const int f0 = (l & 7) * 8;  // first feature owned by this lane
  const int node = blockIdx.x * 16 + (t >> 4);
  if (node >= N) return;
  const int start = rowbeg[node];
  const int end = rowend[node];
  const float ad = aldst[node];

  float ssum = 0.f;
  float acc[8] = {};

  int i0 = start + l;
  bool v0 = i0 < end;
  int s = v0 ? csrc[i0] : 0;
  float w;
  {
    float e = alsrc[s] + ad;
    e = (e > 0.f) ? e : 0.2f * e;  // leaky_relu 0.2
    w = v0 ? __expf(fminf(e, 80.f)) : 0.f;
  }

  for (int base = start; base < end; base += 16) {
    int in = base + 16 + l;
    bool vn = in < end;
    int sn = vn ? csrc[in] : 0;
    float aln = alsrc[sn];

    uint4 u[8];
#pragma unroll
    for (int j = 0; j < 8; ++j) {
      int sj = __shfl(s, gb + 2 * j + half, 64);
      u[j] = *(const uint4*)(hb + (size_t)sj * 64 + f0);
    }

    ssum += w;
#pragma unroll
    for (int j = 0; j < 8; ++j) {
      float wj = __shfl(w, gb + 2 * j + half, 64);
      acc[0] += wj * __uint_as_float(u[j].x << 16);
      acc[1] += wj * __uint_as_float(u[j].x & 0xFFFF0000u);
      acc[2] += wj * __uint_as_float(u[j].y << 16);
      acc[3] += wj * __uint_as_float(u[j].y & 0xFFFF0000u);
      acc[4] += wj * __uint_as_float(u[j].z << 16);
      acc[5] += wj * __uint_as_float(u[j].z & 0xFFFF0000u);
      acc[6] += wj * __uint_as_float(u[j].w << 16);
      acc[7] += wj * __uint_as_float(u[j].w & 0xFFFF0000u);
    }

    float en = aln + ad;
    en = (en > 0.f) ? en : 0.2f * en;
    w = vn ? __expf(fminf(en, 80.f)) : 0.f;
    s = sn;
  }

#pragma unroll
  for (int k = 0; k < 8; ++k) acc[k] += __shfl_xor(acc[k], 8, 64);
#pragma unroll
  for (int off = 1; off < 16; off <<= 1) ssum += __shfl_xor(ssum, off, 64);

  if (half == 0) {
    float inv = 1.0f / ssum;  // >= 1 edge (self-loop)
    float r[8];
#pragma unroll
    for (int k = 0; k < 8; ++k) r[k] = acc[k] * inv;
    if (ELU) {
      const float4 b40 = *(const float4*)(bias + f0);
      const float4 b41 = *(const float4*)(bias + f0 + 4);
      r[0] += b40.x; r[1] += b40.y; r[2] += b40.z; r[3] += b40.w;
      r[4] += b41.x; r[5] += b41.y; r[6] += b41.z; r[7] += b41.w;
#pragma unroll
      for (int k = 0; k < 8; ++k) r[k] = (r[k] > 0.f) ? r[k] : expm1f(r[k]);
    }
    *(float4*)(outbuf + (size_t)node * 64 + f0) = make_float4(r[0], r[1], r[2], r[3]);
    *(float4*)(outbuf + (size_t)node * 64 + f0 + 4) = make_float4(r[4], r[5], r[6], r[7]);
  }
}

// bias + ELU + hierarchical mean-pool accumulation (layer 2) — proven form:
// LDS pre-reduce 16 nodes/block, then 64 atomics per block (400K total).
__global__ __launch_bounds__(256) void post_pool_kernel(
    const float* __restrict__ acc, const float* __restrict__ bias,
    const int* __restrict__ batch, float* __restrict__ pool, int N) {
  __shared__ float4 red4[16][17];
  __shared__ int sB[16];
  __shared__ int uni;
  const int t = threadIdx.x;
  const int ln = t >> 4;
  const int f4 = t & 15;
  const int base = blockIdx.x * 16;
  const int node = base + ln;

  if (t < 16) {
    int nn = base + t;
    sB[t] = (nn < N) ? batch[nn] : -1;
  }
  __syncthreads();
  if (t == 0) {
    int u = (base + 15 < N);
    for (int i = 1; i < 16; i++) u &= (sB[i] == sB[0]);
    uni = u;
  }

  float4 v = make_float4(0.f, 0.f, 0.f, 0.f);
  if (node < N) {
    v = *(const float4*)(acc + ((size_t)node * 16 + f4) * 4);
    const float4 b4 = *(const float4*)(bias + f4 * 4);
    v.x += b4.x; v.y += b4.y; v.z += b4.z; v.w += b4.w;
    v.x = (v.x > 0.f) ? v.x : expm1f(v.x);
    v.y = (v.y > 0.f) ? v.y : expm1f(v.y);
    v.z = (v.z > 0.f) ? v.z : expm1f(v.z);
    v.w = (v.w > 0.f) ? v.w : expm1f(v.w);
  }
  red4[ln][f4] = v;
  __syncthreads();

  if (t < 64) {
    const float* rf = (const float*)red4;  // row stride 68 floats
    if (uni) {
      float s = 0.f;
#pragma unroll
      for (int n = 0; n < 16; n++) s += rf[n * 68 + t];
      atomicAdd(&pool[(size_t)sB[0] * 64 + t], s);
    } else {
      for (int n = 0; n < 16; n++) {
        int g = sB[n];
        if (g >= 0) atomicAdd(&pool[(size_t)g * 64 + t], rf[n * 68 + t]);
      }
    }
  }
}

// out[g] = (pool[g,:]/cnt[g]) . Wfc + bfc ; cnt from sorted-batch bounds.
__global__ void final_kernel(const float* __restrict__ pool, const int* __restrict__ gstart,
                             const float* __restrict__ Wfc, const float* __restrict__ bfc,
                             float* __restrict__ out, int G) {
  int wid = (blockIdx.x * blockDim.x + threadIdx.x) >> 6;
  int lane = threadIdx.x & 63;
  if (wid >= G) return;
  float c = (float)max(gstart[wid + 1] - gstart[wid], 1);
  float v = pool[(size_t)wid * 64 + lane] * (1.0f / c) * Wfc[lane];
  v = wave_reduce_sum(v);
  if (lane == 0) out[wid] = v + bfc[0];
}

// ---------------------------------------------------------------------------

extern "C" void kernel_launch(void* const* d_in, const int* in_sizes, int n_in,
                              void* d_out, int out_size, void* d_ws, size_t ws_size,
                              hipStream_t stream) {
  const float* x     = (const float*)d_in[0];
  const int*   ei    = (const int*)d_in[1];
  const int*   batch = (const int*)d_in[2];
  const float* W1    = (const float*)d_in[3];
  const float* asrc1 = (const float*)d_in[4];
  const float* adst1 = (const float*)d_in[5];
  const float* b1    = (const float*)d_in[6];
  const float* W2    = (const float*)d_in[7];
  const float* asrc2 = (const float*)d_in[8];
  const float* adst2 = (const float*)d_in[9];
  const float* b2    = (const float*)d_in[10];
  const float* Wfc   = (const float*)d_in[11];
  const float* bfc   = (const float*)d_in[12];
  float* out = (float*)d_out;

  const int N = in_sizes[0] / 128;  // 100000
  const int E = in_sizes[1] / 2;    // 1600000
  const int G = 256;
  const int M = E + N;              // edges incl self-loops
  const int NB = (N + BIN_NODES - 1) >> BIN_SHIFT;  // 782 bins

  // workspace carve (256B aligned)
  char* p = (char*)d_ws;
  auto alloc = [&](size_t bytes) {
    char* r = p;
    p += (bytes + 255) & ~size_t(255);
    return r;
  };
  float*          h1e    = (float*)alloc((size_t)N * 64 * 4);
  float*          accbuf = (float*)alloc((size_t)N * 64 * 4);
  unsigned short* hb     = (unsigned short*)alloc((size_t)N * 64 * 2);
  float* alsrc  = (float*)alloc((size_t)N * 4);
  float* aldst  = (float*)alloc((size_t)N * 4);
  int*   rowbeg = (int*)alloc((size_t)N * 4);
  int*   rowend = (int*)alloc((size_t)N * 4);
  int*   csrc   = (int*)alloc((size_t)NB * BIN_CAP * 4);
  unsigned int* binned = (unsigned int*)alloc((size_t)NB * BIN_CAP * 4);
  int*   binCursor = (int*)alloc((size_t)NB * 4);
  float* pool   = (float*)alloc((size_t)G * 64 * 4);
  int*   gstart = (int*)alloc((size_t)(G + 1) * 4);
  unsigned short* w1thi = (unsigned short*)alloc((size_t)64 * 128 * 2);
  unsigned short* w1tlo = (unsigned short*)alloc((size_t)64 * 128 * 2);
  unsigned short* w2thi = (unsigned short*)alloc((size_t)64 * 64 * 2);
  unsigned short* w2tlo = (unsigned short*)alloc((size_t)64 * 64 * 2);

  // ---- fused setup + CSR build ----
  setup_kernel<<<118, 256, 0, stream>>>(W1, w1thi, w1tlo, W2, w2thi, w2tlo,
                                        batch, gstart, binCursor, pool, N, G, NB);
  bin_place_kernel<<<(M + PLACE_CHUNK - 1) / PLACE_CHUNK, 256, 0, stream>>>(
      ei, E, M, NB, binCursor, binned);
  csr_finalize_kernel<<<NB, 512, 0, stream>>>(binned, binCursor, rowbeg, rowend,
                                              csrc, N, NB);

  // ---- layer 1 ----
  gemm_mfma<128><<<(N + 63) / 64, 256, 0, stream>>>(x, w1thi, w1tlo, hb, asrc1, adst1,
                                                    alsrc, aldst, N);
  spmm_fused_kernel<1><<<(N + 15) / 16, 256, 0, stream>>>(rowbeg, rowend, csrc, alsrc,
                                                          aldst, hb, b1, h1e, N);

  // ---- layer 2 ----
  gemm_mfma<64><<<(N + 63) / 64, 256, 0, stream>>>(h1e, w2thi, w2tlo, hb, asrc2, adst2,
                                                   alsrc, aldst, N);
  spmm_fused_kernel<0><<<(N + 15) / 16, 256, 0, stream>>>(rowbeg, rowend, csrc, alsrc,
                                                          aldst, hb, nullptr, accbuf, N);
  post_pool_kernel<<<(N + 15) / 16, 256, 0, stream>>>(accbuf, b2, batch, pool, N);

  // ---- readout ----
  final_kernel<<<(G * 64 + 255) / 256, 256, 0, stream>>>(pool, gstart, Wfc, bfc, out, G);
}

// Round 11
// 264.723 us; speedup vs baseline: 1.4865x; 1.0182x over previous
//
#include <hip/hip_runtime.h>
#include <hip/hip_bf16.h>
#include <cstdint>

// ---------------------------------------------------------------------------
// GAT 2-layer model on MI355X.
// R14-R16: spmm gather loop pinned at ~42us by the random-gather L2-miss
//   path (~2.75 TB/s invariant). Hot loop FROZEN.
// R17 (WIN): GEMMs on bf16 MFMA via LDS staging, split precision.
// R18 (REGR): device-wide scatter CSR. Lesson: scatter stays window-confined.
// R19 (REGR): LDS-free gemm. Lesson: barrier-paced staging is load-bearing.
// R20 (WIN 279.1->268.4): fused setup kernel, finalize@512t.
// R21/R22 (REGR): pool fused into spmm epilogue -> 1.6M device atomics,
//   51MB write-amp. Lesson: always block-level pre-reduce before atomics.
// R23: revert fusion; BIN_SHIFT 7 kept (neutral). 269.5us. Budget: spmm 84,
//   remaining 7 kernels ~185 (each <41.8, none dominant), launch ~2.7/kernel.
// R24: dependency-graph re-packing (no inner-loop changes):
//   MEGA_A = setup  ∪ bin_place   (independent, both 256t, 8KB LDS)
//   MEGA_B = finalize ∪ gemm128   (independent: finalize needs bin_place,
//            gemm128 needs only x+W1-presplit; 256t; finalize uses a carve
//            of the gemm's 80KB LDS). Serial ~65us -> concurrent ~max.
// ---------------------------------------------------------------------------

#define BIN_SHIFT 7
#define BIN_NODES 128
#define BIN_CAP 3584
#define PLACE_CHUNK 2048
#define SETUP_BLOCKS 114  // 32 wsplitW1 + 16 wsplitW2 + 2 bounds + 64 poolzero

typedef __attribute__((ext_vector_type(8))) short bf16x8;
typedef __attribute__((ext_vector_type(4))) float f32x4;

__device__ __forceinline__ float wave_reduce_sum(float v) {
#pragma unroll
  for (int off = 32; off > 0; off >>= 1) v += __shfl_xor(v, off, 64);
  return v;
}

__device__ __forceinline__ unsigned short f2bf(float f) {  // RNE
  unsigned int u = __float_as_uint(f);
  u += 0x7fffu + ((u >> 16) & 1u);
  return (unsigned short)(u >> 16);
}
__device__ __forceinline__ float bf2f(unsigned short u) {
  return __uint_as_float(((unsigned int)u) << 16);
}

// ---------------- MEGA_A: setup ∪ bin_place ----------------
// Blocks [0,32): wsplit W1; [32,48): wsplit W2; [48,50): bounds;
// [50,114): zero pool; [114, 114+NPLACE): bin_place.
__global__ __launch_bounds__(256) void mega_a_kernel(
    const float* __restrict__ W1, unsigned short* __restrict__ w1thi,
    unsigned short* __restrict__ w1tlo, const float* __restrict__ W2,
    unsigned short* __restrict__ w2thi, unsigned short* __restrict__ w2tlo,
    const int* __restrict__ batch, int* __restrict__ gstart,
    float* __restrict__ pool, const int* __restrict__ ei, int E, int M,
    int NB, int* __restrict__ binCursor, unsigned int* __restrict__ binned,
    int N, int G) {
  __shared__ int cur[1024];
  __shared__ int res[1024];
  const int b = blockIdx.x;
  const int t = threadIdx.x;

  if (b < 32) {
    int idx = b * 256 + t;  // < 8192 = 128*64
    int n = idx & 63, k = idx >> 6;
    float v = W1[(size_t)k * 64 + n];
    unsigned short h = f2bf(v);
    w1thi[(size_t)n * 128 + k] = h;
    w1tlo[(size_t)n * 128 + k] = f2bf(v - bf2f(h));
    return;
  } else if (b < 48) {
    int idx = (b - 32) * 256 + t;  // < 4096 = 64*64
    int n = idx & 63, k = idx >> 6;
    float v = W2[(size_t)k * 64 + n];
    unsigned short h = f2bf(v);
    w2thi[(size_t)n * 64 + k] = h;
    w2tlo[(size_t)n * 64 + k] = f2bf(v - bf2f(h));
    return;
  } else if (b < 50) {
    int g = (b - 48) * 256 + t;
    if (g <= G) {
      int lo = 0, hi = N;
      while (lo < hi) {
        int mid = (lo + hi) >> 1;
        if (batch[mid] < g) lo = mid + 1;
        else hi = mid;
      }
      gstart[g] = lo;
    }
    return;
  } else if (b < SETUP_BLOCKS) {
    int i = (b - 50) * 256 + t;  // < 16384
    pool[i] = 0.f;
    return;
  }

  // ---- bin_place path ----
  const int cbase = (b - SETUP_BLOCKS) * PLACE_CHUNK;
  for (int i = t; i < NB; i += 256) cur[i] = 0;
  __syncthreads();

  unsigned int pk[PLACE_CHUNK / 256];
  int br[PLACE_CHUNK / 256];
#pragma unroll
  for (int j = 0; j < PLACE_CHUNK / 256; ++j) {
    int i = cbase + t + j * 256;
    if (i < M) {
      int s, d;
      if (i < E) { s = ei[i]; d = ei[E + i]; } else { s = d = i - E; }
      int bb = d >> BIN_SHIFT;
      int r = atomicAdd(&cur[bb], 1);
      pk[j] = ((unsigned int)(d & (BIN_NODES - 1)) << 24) | (unsigned int)s;
      br[j] = (bb << 16) | r;
    } else {
      br[j] = -1;
    }
  }
  __syncthreads();
  for (int i = t; i < NB; i += 256) {
    int c = cur[i];
    res[i] = c ? atomicAdd(&binCursor[i], c) : 0;
  }
  __syncthreads();
#pragma unroll
  for (int j = 0; j < PLACE_CHUNK / 256; ++j) {
    if (br[j] >= 0) {
      int bb = br[j] >> 16;
      int pos = res[bb] + (br[j] & 0xFFFF);
      if (pos < BIN_CAP) binned[(size_t)bb * BIN_CAP + pos] = pk[j];
    }
  }
}

// ---------------- MEGA_B: csr_finalize ∪ gemm128 ----------------
// Blocks [0,NB): finalize (LDS carved from gemm arrays); [NB, NB+(N+63)/64):
// gemm_mfma<128> (R17 proven body, verbatim).
__global__ __launch_bounds__(256) void finalize_gemm_kernel(
    const unsigned int* __restrict__ binned, const int* __restrict__ binCursor,
    int* __restrict__ rowbeg, int* __restrict__ rowend, int* __restrict__ csrc,
    int NB,
    const float* __restrict__ A, const unsigned short* __restrict__ Wt_hi,
    const unsigned short* __restrict__ Wt_lo, unsigned short* __restrict__ hb,
    const float* __restrict__ a_src, const float* __restrict__ a_dst,
    float* __restrict__ alsrc, float* __restrict__ aldst, int N) {
  __shared__ unsigned short Ah[64][40], Al[64][40], Bh[64][40], Bl[64][40];
  const int t = threadIdx.x;

  if (blockIdx.x < NB) {
    // ---- finalize path (256t; cnt/wsum carved from Ah/Bh) ----
    int* cnt = (int*)&Ah[0][0];    // 128 ints
    int* wsum = (int*)&Bh[0][0];   // 2 ints
    const int b = blockIdx.x;
    const int nodeBase = b << BIN_SHIFT;
    const int eBase = b * BIN_CAP;
    const int cntE = binCursor[b];

    if (t < 128) cnt[t] = 0;
    __syncthreads();
    for (int i = t; i < cntE; i += 256) {
      atomicAdd(&cnt[binned[eBase + i] >> 24], 1);
    }
    __syncthreads();
    const int lane = t & 63, wv = t >> 6;
    int v = (t < 128) ? cnt[t] : 0;
    int x = v;
#pragma unroll
    for (int o = 1; o < 64; o <<= 1) {
      int u = __shfl_up(x, o, 64);
      if (lane >= o) x += u;
    }
    if (t < 128 && lane == 63) wsum[wv] = x;
    __syncthreads();
    if (t < 128) {
      const int o = ((wv == 1) ? wsum[0] : 0) + x - v;
      int node = nodeBase + t;
      if (node < N) {
        rowbeg[node] = eBase + o;
        rowend[node] = eBase + o + v;
      }
      cnt[t] = o;  // reuse as cursor
    }
    __syncthreads();
    for (int i = t; i < cntE; i += 256) {
      unsigned int pk = binned[eBase + i];
      int r = atomicAdd(&cnt[pk >> 24], 1);
      csrc[eBase + r] = (int)(pk & 0xFFFFFFu);
    }
    return;
  }

  // ---- gemm128 path (R17 body) ----
  constexpr int KDIM = 128;
  const int block_m = (blockIdx.x - NB) * 64;
  const int lane = t & 63;
  const int m0 = (t >> 6) * 16;
  const int lc = lane & 15;
  const int lr = lane >> 4;
  const int srow = t >> 2;
  const int skslot = (t & 3) * 8;

  f32x4 acc[4] = {};

  for (int kc = 0; kc < KDIM; kc += 32) {
    {
      int gn = block_m + srow;
      if (gn >= N) gn = N - 1;
      const float4 v0 = *(const float4*)(A + (size_t)gn * KDIM + kc + skslot);
      const float4 v1 = *(const float4*)(A + (size_t)gn * KDIM + kc + skslot + 4);
      float v[8] = {v0.x, v0.y, v0.z, v0.w, v1.x, v1.y, v1.z, v1.w};
      unsigned short h8[8], l8[8];
#pragma unroll
      for (int j = 0; j < 8; ++j) {
        h8[j] = f2bf(v[j]);
        l8[j] = f2bf(v[j] - bf2f(h8[j]));
      }
      *(uint4*)&Ah[srow][skslot] = *(const uint4*)h8;
      *(uint4*)&Al[srow][skslot] = *(const uint4*)l8;
    }
    {
      const uint4 wh = *(const uint4*)(Wt_hi + (size_t)srow * KDIM + kc + skslot);
      const uint4 wl = *(const uint4*)(Wt_lo + (size_t)srow * KDIM + kc + skslot);
      *(uint4*)&Bh[srow][skslot] = wh;
      *(uint4*)&Bl[srow][skslot] = wl;
    }
    __syncthreads();

    const bf16x8 ah = *(const bf16x8*)&Ah[m0 + lc][lr * 8];
    const bf16x8 al = *(const bf16x8*)&Al[m0 + lc][lr * 8];
#pragma unroll
    for (int nf = 0; nf < 4; ++nf) {
      const bf16x8 bh = *(const bf16x8*)&Bh[nf * 16 + lc][lr * 8];
      const bf16x8 bl = *(const bf16x8*)&Bl[nf * 16 + lc][lr * 8];
      acc[nf] = __builtin_amdgcn_mfma_f32_16x16x32_bf16(ah, bh, acc[nf], 0, 0, 0);
      acc[nf] = __builtin_amdgcn_mfma_f32_16x16x32_bf16(ah, bl, acc[nf], 0, 0, 0);
      acc[nf] = __builtin_amdgcn_mfma_f32_16x16x32_bf16(al, bh, acc[nf], 0, 0, 0);
    }
    __syncthreads();
  }

  float as4[4], ad4[4];
#pragma unroll
  for (int nf = 0; nf < 4; ++nf) {
    as4[nf] = a_src[nf * 16 + lc];
    ad4[nf] = a_dst[nf * 16 + lc];
  }
#pragma unroll
  for (int r = 0; r < 4; ++r) {
    const int gn = block_m + m0 + lr * 4 + r;
    float ps = 0.f, pd = 0.f;
#pragma unroll
    for (int nf = 0; nf < 4; ++nf) {
      const float v = acc[nf][r];
      if (gn < N) hb[(size_t)gn * 64 + nf * 16 + lc] = f2bf(v);
      ps += v * as4[nf];
      pd += v * ad4[nf];
    }
#pragma unroll
    for (int off = 1; off < 16; off <<= 1) {
      ps += __shfl_xor(ps, off, 64);
      pd += __shfl_xor(pd, off, 64);
    }
    if (lc == 0 && gn < N) {
      alsrc[gn] = ps;
      aldst[gn] = pd;
    }
  }
}

// ---------------- dense compute (layer 2 gemm, R17 form) ----------------

template <int KDIM>
__global__ __launch_bounds__(256) void gemm_mfma(
    const float* __restrict__ A, const unsigned short* __restrict__ Wt_hi,
    const unsigned short* __restrict__ Wt_lo, unsigned short* __restrict__ hb,
    const float* __restrict__ a_src, const float* __restrict__ a_dst,
    float* __restrict__ alsrc, float* __restrict__ aldst, int N) {
  __shared__ unsigned short Ah[64][40], Al[64][40], Bh[64][40], Bl[64][40];
  const int block_m = blockIdx.x * 64;
  const int t = threadIdx.x;
  const int lane = t & 63;
  const int m0 = (t >> 6) * 16;
  const int lc = lane & 15;
  const int lr = lane >> 4;
  const int srow = t >> 2;
  const int skslot = (t & 3) * 8;

  f32x4 acc[4] = {};

  for (int kc = 0; kc < KDIM; kc += 32) {
    {
      int gn = block_m + srow;
      if (gn >= N) gn = N - 1;
      const float4 v0 = *(const float4*)(A + (size_t)gn * KDIM + kc + skslot);
      const float4 v1 = *(const float4*)(A + (size_t)gn * KDIM + kc + skslot + 4);
      float v[8] = {v0.x, v0.y, v0.z, v0.w, v1.x, v1.y, v1.z, v1.w};
      unsigned short h8[8], l8[8];
#pragma unroll
      for (int j = 0; j < 8; ++j) {
        h8[j] = f2bf(v[j]);
        l8[j] = f2bf(v[j] - bf2f(h8[j]));
      }
      *(uint4*)&Ah[srow][skslot] = *(const uint4*)h8;
      *(uint4*)&Al[srow][skslot] = *(const uint4*)l8;
    }
    {
      const uint4 wh = *(const uint4*)(Wt_hi + (size_t)srow * KDIM + kc + skslot);
      const uint4 wl = *(const uint4*)(Wt_lo + (size_t)srow * KDIM + kc + skslot);
      *(uint4*)&Bh[srow][skslot] = wh;
      *(uint4*)&Bl[srow][skslot] = wl;
    }
    __syncthreads();

    const bf16x8 ah = *(const bf16x8*)&Ah[m0 + lc][lr * 8];
    const bf16x8 al = *(const bf16x8*)&Al[m0 + lc][lr * 8];
#pragma unroll
    for (int nf = 0; nf < 4; ++nf) {
      const bf16x8 bh = *(const bf16x8*)&Bh[nf * 16 + lc][lr * 8];
      const bf16x8 bl = *(const bf16x8*)&Bl[nf * 16 + lc][lr * 8];
      acc[nf] = __builtin_amdgcn_mfma_f32_16x16x32_bf16(ah, bh, acc[nf], 0, 0, 0);
      acc[nf] = __builtin_amdgcn_mfma_f32_16x16x32_bf16(ah, bl, acc[nf], 0, 0, 0);
      acc[nf] = __builtin_amdgcn_mfma_f32_16x16x32_bf16(al, bh, acc[nf], 0, 0, 0);
    }
    __syncthreads();
  }

  float as4[4], ad4[4];
#pragma unroll
  for (int nf = 0; nf < 4; ++nf) {
    as4[nf] = a_src[nf * 16 + lc];
    ad4[nf] = a_dst[nf * 16 + lc];
  }
#pragma unroll
  for (int r = 0; r < 4; ++r) {
    const int gn = block_m + m0 + lr * 4 + r;
    float ps = 0.f, pd = 0.f;
#pragma unroll
    for (int nf = 0; nf < 4; ++nf) {
      const float v = acc[nf][r];
      if (gn < N) hb[(size_t)gn * 64 + nf * 16 + lc] = f2bf(v);
      ps += v * as4[nf];
      pd += v * ad4[nf];
    }
#pragma unroll
    for (int off = 1; off < 16; off <<= 1) {
      ps += __shfl_xor(ps, off, 64);
      pd += __shfl_xor(pd, off, 64);
    }
    if (lc == 0 && gn < N) {
      alsrc[gn] = ps;
      aldst[gn] = pd;
    }
  }
}

// Fused no-max softmax + spmm (R16 hot loop, frozen; R20 epilogue form).
template <int ELU>
__global__ __launch_bounds__(256) void spmm_fused_kernel(
    const int* __restrict__ rowbeg, const int* __restrict__ rowend,
    const int* __restrict__ csrc,
    const float* __restrict__ alsrc, const float* __restrict__ aldst,
    const unsigned short* __restrict__ hb, const float* __restrict__ bias,
    float* __restrict__ outbuf, int N) {
  const int t = threadIdx.x;
  const int l = t & 15;        // slot within group
  const int gb = t & 48;       // group base lane within wave
  const int half = l >> 3;     // which edge of the pair this lane serves
  const int f0 = (l & 7) * 8;  // first feature owned by this lane
  const int node = blockIdx.x * 16 + (t >> 4);
  if (node >= N) return;
  const int start = rowbeg[node];
  const int end = rowend[node];
  const float ad = aldst[node];

  float ssum = 0.f;
  float acc[8] = {};

  int i0 = start + l;
  bool v0 = i0 < end;
  int s = v0 ? csrc[i0] : 0;
  float w;
  {
    float e = alsrc[s] + ad;
    e = (e > 0.f) ? e : 0.2f * e;  // leaky_relu 0.2
    w = v0 ? __expf(fminf(e, 80.f)) : 0.f;
  }

  for (int base = start; base < end; base += 16) {
    int in = base + 16 + l;
    bool vn = in < end;
    int sn = vn ? csrc[in] : 0;
    float aln = alsrc[sn];

    uint4 u[8];
#pragma unroll
    for (int j = 0; j < 8; ++j) {
      int sj = __shfl(s, gb + 2 * j + half, 64);
      u[j] = *(const uint4*)(hb + (size_t)sj * 64 + f0);
    }

    ssum += w;
#pragma unroll
    for (int j = 0; j < 8; ++j) {
      float wj = __shfl(w, gb + 2 * j + half, 64);
      acc[0] += wj * __uint_as_float(u[j].x << 16);
      acc[1] += wj * __uint_as_float(u[j].x & 0xFFFF0000u);
      acc[2] += wj * __uint_as_float(u[j].y << 16);
      acc[3] += wj * __uint_as_float(u[j].y & 0xFFFF0000u);
      acc[4] += wj * __uint_as_float(u[j].z << 16);
      acc[5] += wj * __uint_as_float(u[j].z & 0xFFFF0000u);
      acc[6] += wj * __uint_as_float(u[j].w << 16);
      acc[7] += wj * __uint_as_float(u[j].w & 0xFFFF0000u);
    }

    float en = aln + ad;
    en = (en > 0.f) ? en : 0.2f * en;
    w = vn ? __expf(fminf(en, 80.f)) : 0.f;
    s = sn;
  }

#pragma unroll
  for (int k = 0; k < 8; ++k) acc[k] += __shfl_xor(acc[k], 8, 64);
#pragma unroll
  for (int off = 1; off < 16; off <<= 1) ssum += __shfl_xor(ssum, off, 64);

  if (half == 0) {
    float inv = 1.0f / ssum;  // >= 1 edge (self-loop)
    float r[8];
#pragma unroll
    for (int k = 0; k < 8; ++k) r[k] = acc[k] * inv;
    if (ELU) {
      const float4 b40 = *(const float4*)(bias + f0);
      const float4 b41 = *(const float4*)(bias + f0 + 4);
      r[0] += b40.x; r[1] += b40.y; r[2] += b40.z; r[3] += b40.w;
      r[4] += b41.x; r[5] += b41.y; r[6] += b41.z; r[7] += b41.w;
#pragma unroll
      for (int k = 0; k < 8; ++k) r[k] = (r[k] > 0.f) ? r[k] : expm1f(r[k]);
    }
    *(float4*)(outbuf + (size_t)node * 64 + f0) = make_float4(r[0], r[1], r[2], r[3]);
    *(float4*)(outbuf + (size_t)node * 64 + f0 + 4) = make_float4(r[4], r[5], r[6], r[7]);
  }
}

// bias + ELU + hierarchical mean-pool accumulation (layer 2) — proven form:
// LDS pre-reduce 16 nodes/block, then 64 atomics per block (400K total).
__global__ __launch_bounds__(256) void post_pool_kernel(
    const float* __restrict__ acc, const float* __restrict__ bias,
    const int* __restrict__ batch, float* __restrict__ pool, int N) {
  __shared__ float4 red4[16][17];
  __shared__ int sB[16];
  __shared__ int uni;
  const int t = threadIdx.x;
  const int ln = t >> 4;
  const int f4 = t & 15;
  const int base = blockIdx.x * 16;
  const int node = base + ln;

  if (t < 16) {
    int nn = base + t;
    sB[t] = (nn < N) ? batch[nn] : -1;
  }
  __syncthreads();
  if (t == 0) {
    int u = (base + 15 < N);
    for (int i = 1; i < 16; i++) u &= (sB[i] == sB[0]);
    uni = u;
  }

  float4 v = make_float4(0.f, 0.f, 0.f, 0.f);
  if (node < N) {
    v = *(const float4*)(acc + ((size_t)node * 16 + f4) * 4);
    const float4 b4 = *(const float4*)(bias + f4 * 4);
    v.x += b4.x; v.y += b4.y; v.z += b4.z; v.w += b4.w;
    v.x = (v.x > 0.f) ? v.x : expm1f(v.x);
    v.y = (v.y > 0.f) ? v.y : expm1f(v.y);
    v.z = (v.z > 0.f) ? v.z : expm1f(v.z);
    v.w = (v.w > 0.f) ? v.w : expm1f(v.w);
  }
  red4[ln][f4] = v;
  __syncthreads();

  if (t < 64) {
    const float* rf = (const float*)red4;  // row stride 68 floats
    if (uni) {
      float s = 0.f;
#pragma unroll
      for (int n = 0; n < 16; n++) s += rf[n * 68 + t];
      atomicAdd(&pool[(size_t)sB[0] * 64 + t], s);
    } else {
      for (int n = 0; n < 16; n++) {
        int g = sB[n];
        if (g >= 0) atomicAdd(&pool[(size_t)g * 64 + t], rf[n * 68 + t]);
      }
    }
  }
}

// out[g] = (pool[g,:]/cnt[g]) . Wfc + bfc ; cnt from sorted-batch bounds.
__global__ void final_kernel(const float* __restrict__ pool, const int* __restrict__ gstart,
                             const float* __restrict__ Wfc, const float* __restrict__ bfc,
                             float* __restrict__ out, int G) {
  int wid = (blockIdx.x * blockDim.x + threadIdx.x) >> 6;
  int lane = threadIdx.x & 63;
  if (wid >= G) return;
  float c = (float)max(gstart[wid + 1] - gstart[wid], 1);
  float v = pool[(size_t)wid * 64 + lane] * (1.0f / c) * Wfc[lane];
  v = wave_reduce_sum(v);
  if (lane == 0) out[wid] = v + bfc[0];
}

// ---------------------------------------------------------------------------

extern "C" void kernel_launch(void* const* d_in, const int* in_sizes, int n_in,
                              void* d_out, int out_size, void* d_ws, size_t ws_size,
                              hipStream_t stream) {
  const float* x     = (const float*)d_in[0];
  const int*   ei    = (const int*)d_in[1];
  const int*   batch = (const int*)d_in[2];
  const float* W1    = (const float*)d_in[3];
  const float* asrc1 = (const float*)d_in[4];
  const float* adst1 = (const float*)d_in[5];
  const float* b1    = (const float*)d_in[6];
  const float* W2    = (const float*)d_in[7];
  const float* asrc2 = (const float*)d_in[8];
  const float* adst2 = (const float*)d_in[9];
  const float* b2    = (const float*)d_in[10];
  const float* Wfc   = (const float*)d_in[11];
  const float* bfc   = (const float*)d_in[12];
  float* out = (float*)d_out;

  const int N = in_sizes[0] / 128;  // 100000
  const int E = in_sizes[1] / 2;    // 1600000
  const int G = 256;
  const int M = E + N;              // edges incl self-loops
  const int NB = (N + BIN_NODES - 1) >> BIN_SHIFT;  // 782 bins
  const int NPLACE = (M + PLACE_CHUNK - 1) / PLACE_CHUNK;

  // workspace carve (256B aligned)
  char* p = (char*)d_ws;
  auto alloc = [&](size_t bytes) {
    char* r = p;
    p += (bytes + 255) & ~size_t(255);
    return r;
  };
  float*          h1e    = (float*)alloc((size_t)N * 64 * 4);
  float*          accbuf = (float*)alloc((size_t)N * 64 * 4);
  unsigned short* hb     = (unsigned short*)alloc((size_t)N * 64 * 2);
  float* alsrc  = (float*)alloc((size_t)N * 4);
  float* aldst  = (float*)alloc((size_t)N * 4);
  int*   rowbeg = (int*)alloc((size_t)N * 4);
  int*   rowend = (int*)alloc((size_t)N * 4);
  int*   csrc   = (int*)alloc((size_t)NB * BIN_CAP * 4);
  unsigned int* binned = (unsigned int*)alloc((size_t)NB * BIN_CAP * 4);
  int*   binCursor = (int*)alloc((size_t)NB * 4);
  float* pool   = (float*)alloc((size_t)G * 64 * 4);
  int*   gstart = (int*)alloc((size_t)(G + 1) * 4);
  unsigned short* w1thi = (unsigned short*)alloc((size_t)64 * 128 * 2);
  unsigned short* w1tlo = (unsigned short*)alloc((size_t)64 * 128 * 2);
  unsigned short* w2thi = (unsigned short*)alloc((size_t)64 * 64 * 2);
  unsigned short* w2tlo = (unsigned short*)alloc((size_t)64 * 64 * 2);

  // ---- stage 1: zero binCursor, then MEGA_A (setup ∪ bin_place) ----
  hipMemsetAsync(binCursor, 0, (size_t)NB * 4, stream);
  mega_a_kernel<<<SETUP_BLOCKS + NPLACE, 256, 0, stream>>>(
      W1, w1thi, w1tlo, W2, w2thi, w2tlo, batch, gstart, pool,
      ei, E, M, NB, binCursor, binned, N, G);

  // ---- stage 2: MEGA_B (finalize ∪ gemm128) ----
  finalize_gemm_kernel<<<NB + (N + 63) / 64, 256, 0, stream>>>(
      binned, binCursor, rowbeg, rowend, csrc, NB,
      x, w1thi, w1tlo, hb, asrc1, adst1, alsrc, aldst, N);

  // ---- layer 1 spmm ----
  spmm_fused_kernel<1><<<(N + 15) / 16, 256, 0, stream>>>(rowbeg, rowend, csrc, alsrc,
                                                          aldst, hb, b1, h1e, N);

  // ---- layer 2 ----
  gemm_mfma<64><<<(N + 63) / 64, 256, 0, stream>>>(h1e, w2thi, w2tlo, hb, asrc2, adst2,
                                                   alsrc, aldst, N);
  spmm_fused_kernel<0><<<(N + 15) / 16, 256, 0, stream>>>(rowbeg, rowend, csrc, alsrc,
                                                          aldst, hb, nullptr, accbuf, N);
  post_pool_kernel<<<(N + 15) / 16, 256, 0, stream>>>(accbuf, b2, batch, pool, N);

  // ---- readout ----
  final_kernel<<<(G * 64 + 255) / 256, 256, 0, stream>>>(pool, gstart, Wfc, bfc, out, G);
}

// Round 12
// 260.990 us; speedup vs baseline: 1.5078x; 1.0143x over previous
//
#include <hip/hip_runtime.h>
#include <hip/hip_bf16.h>
#include <cstdint>

// ---------------------------------------------------------------------------
// GAT 2-layer model on MI355X.
// R14-R16: spmm gather loop pinned at ~42us: FETCH ~= compulsory per-XCD L2
//   fill of hb (8 x 12.8MB) through the ~2.75TB/s L3->L2 path. Hot loop
//   FROZEN; byte-reduction blocked by precision (bf16 needed).
// R17 (WIN): GEMMs on bf16 MFMA via LDS staging, split precision.
// R18 (REGR): device-wide scatter CSR. Lesson: scatter stays window-confined.
// R19 (REGR): LDS-free gemm. Lesson: barrier-paced staging is load-bearing.
// R20 (WIN): fused setup kernel, finalize@512t.
// R21/R22 (REGR): pool fused as RAW per-wave atomics (1.6M, 51MB write-amp).
//   Lesson: always block-level pre-reduce before device atomics.
// R23: revert; BIN_SHIFT 7 kept. 269.5us.
// R24 (WIN 269.5->264.7): MEGA_A = setup ∪ bin_place; MEGA_B = finalize ∪
//   gemm128 (independent work co-scheduled in one launch).
// R25: post_pool fused into spmm<0> THE RIGHT WAY: hot loop byte-identical;
//   epilogue stages 16 biased+ELU rows into 4.4KB LDS (stride-68), one
//   syncthreads, then post_pool's reduce -> 64 atomics/block (400K total,
//   same as standalone). Deletes accbuf 51.2MB round-trip + a launch.
// ---------------------------------------------------------------------------

#define BIN_SHIFT 7
#define BIN_NODES 128
#define BIN_CAP 3584
#define PLACE_CHUNK 2048
#define SETUP_BLOCKS 114  // 32 wsplitW1 + 16 wsplitW2 + 2 bounds + 64 poolzero

typedef __attribute__((ext_vector_type(8))) short bf16x8;
typedef __attribute__((ext_vector_type(4))) float f32x4;

__device__ __forceinline__ float wave_reduce_sum(float v) {
#pragma unroll
  for (int off = 32; off > 0; off >>= 1) v += __shfl_xor(v, off, 64);
  return v;
}

__device__ __forceinline__ unsigned short f2bf(float f) {  // RNE
  unsigned int u = __float_as_uint(f);
  u += 0x7fffu + ((u >> 16) & 1u);
  return (unsigned short)(u >> 16);
}
__device__ __forceinline__ float bf2f(unsigned short u) {
  return __uint_as_float(((unsigned int)u) << 16);
}

// ---------------- MEGA_A: setup ∪ bin_place ----------------
__global__ __launch_bounds__(256) void mega_a_kernel(
    const float* __restrict__ W1, unsigned short* __restrict__ w1thi,
    unsigned short* __restrict__ w1tlo, const float* __restrict__ W2,
    unsigned short* __restrict__ w2thi, unsigned short* __restrict__ w2tlo,
    const int* __restrict__ batch, int* __restrict__ gstart,
    float* __restrict__ pool, const int* __restrict__ ei, int E, int M,
    int NB, int* __restrict__ binCursor, unsigned int* __restrict__ binned,
    int N, int G) {
  __shared__ int cur[1024];
  __shared__ int res[1024];
  const int b = blockIdx.x;
  const int t = threadIdx.x;

  if (b < 32) {
    int idx = b * 256 + t;  // < 8192 = 128*64
    int n = idx & 63, k = idx >> 6;
    float v = W1[(size_t)k * 64 + n];
    unsigned short h = f2bf(v);
    w1thi[(size_t)n * 128 + k] = h;
    w1tlo[(size_t)n * 128 + k] = f2bf(v - bf2f(h));
    return;
  } else if (b < 48) {
    int idx = (b - 32) * 256 + t;  // < 4096 = 64*64
    int n = idx & 63, k = idx >> 6;
    float v = W2[(size_t)k * 64 + n];
    unsigned short h = f2bf(v);
    w2thi[(size_t)n * 64 + k] = h;
    w2tlo[(size_t)n * 64 + k] = f2bf(v - bf2f(h));
    return;
  } else if (b < 50) {
    int g = (b - 48) * 256 + t;
    if (g <= G) {
      int lo = 0, hi = N;
      while (lo < hi) {
        int mid = (lo + hi) >> 1;
        if (batch[mid] < g) lo = mid + 1;
        else hi = mid;
      }
      gstart[g] = lo;
    }
    return;
  } else if (b < SETUP_BLOCKS) {
    int i = (b - 50) * 256 + t;  // < 16384
    pool[i] = 0.f;
    return;
  }

  // ---- bin_place path ----
  const int cbase = (b - SETUP_BLOCKS) * PLACE_CHUNK;
  for (int i = t; i < NB; i += 256) cur[i] = 0;
  __syncthreads();

  unsigned int pk[PLACE_CHUNK / 256];
  int br[PLACE_CHUNK / 256];
#pragma unroll
  for (int j = 0; j < PLACE_CHUNK / 256; ++j) {
    int i = cbase + t + j * 256;
    if (i < M) {
      int s, d;
      if (i < E) { s = ei[i]; d = ei[E + i]; } else { s = d = i - E; }
      int bb = d >> BIN_SHIFT;
      int r = atomicAdd(&cur[bb], 1);
      pk[j] = ((unsigned int)(d & (BIN_NODES - 1)) << 24) | (unsigned int)s;
      br[j] = (bb << 16) | r;
    } else {
      br[j] = -1;
    }
  }
  __syncthreads();
  for (int i = t; i < NB; i += 256) {
    int c = cur[i];
    res[i] = c ? atomicAdd(&binCursor[i], c) : 0;
  }
  __syncthreads();
#pragma unroll
  for (int j = 0; j < PLACE_CHUNK / 256; ++j) {
    if (br[j] >= 0) {
      int bb = br[j] >> 16;
      int pos = res[bb] + (br[j] & 0xFFFF);
      if (pos < BIN_CAP) binned[(size_t)bb * BIN_CAP + pos] = pk[j];
    }
  }
}

// ---------------- MEGA_B: csr_finalize ∪ gemm128 ----------------
__global__ __launch_bounds__(256) void finalize_gemm_kernel(
    const unsigned int* __restrict__ binned, const int* __restrict__ binCursor,
    int* __restrict__ rowbeg, int* __restrict__ rowend, int* __restrict__ csrc,
    int NB,
    const float* __restrict__ A, const unsigned short* __restrict__ Wt_hi,
    const unsigned short* __restrict__ Wt_lo, unsigned short* __restrict__ hb,
    const float* __restrict__ a_src, const float* __restrict__ a_dst,
    float* __restrict__ alsrc, float* __restrict__ aldst, int N) {
  __shared__ unsigned short Ah[64][40], Al[64][40], Bh[64][40], Bl[64][40];
  const int t = threadIdx.x;

  if (blockIdx.x < NB) {
    // ---- finalize path (256t; cnt/wsum carved from Ah/Bh) ----
    int* cnt = (int*)&Ah[0][0];    // 128 ints
    int* wsum = (int*)&Bh[0][0];   // 2 ints
    const int b = blockIdx.x;
    const int nodeBase = b << BIN_SHIFT;
    const int eBase = b * BIN_CAP;
    const int cntE = binCursor[b];

    if (t < 128) cnt[t] = 0;
    __syncthreads();
    for (int i = t; i < cntE; i += 256) {
      atomicAdd(&cnt[binned[eBase + i] >> 24], 1);
    }
    __syncthreads();
    const int lane = t & 63, wv = t >> 6;
    int v = (t < 128) ? cnt[t] : 0;
    int x = v;
#pragma unroll
    for (int o = 1; o < 64; o <<= 1) {
      int u = __shfl_up(x, o, 64);
      if (lane >= o) x += u;
    }
    if (t < 128 && lane == 63) wsum[wv] = x;
    __syncthreads();
    if (t < 128) {
      const int o = ((wv == 1) ? wsum[0] : 0) + x - v;
      int node = nodeBase + t;
      if (node < N) {
        rowbeg[node] = eBase + o;
        rowend[node] = eBase + o + v;
      }
      cnt[t] = o;  // reuse as cursor
    }
    __syncthreads();
    for (int i = t; i < cntE; i += 256) {
      unsigned int pk = binned[eBase + i];
      int r = atomicAdd(&cnt[pk >> 24], 1);
      csrc[eBase + r] = (int)(pk & 0xFFFFFFu);
    }
    return;
  }

  // ---- gemm128 path (R17 body) ----
  constexpr int KDIM = 128;
  const int block_m = (blockIdx.x - NB) * 64;
  const int lane = t & 63;
  const int m0 = (t >> 6) * 16;
  const int lc = lane & 15;
  const int lr = lane >> 4;
  const int srow = t >> 2;
  const int skslot = (t & 3) * 8;

  f32x4 acc[4] = {};

  for (int kc = 0; kc < KDIM; kc += 32) {
    {
      int gn = block_m + srow;
      if (gn >= N) gn = N - 1;
      const float4 v0 = *(const float4*)(A + (size_t)gn * KDIM + kc + skslot);
      const float4 v1 = *(const float4*)(A + (size_t)gn * KDIM + kc + skslot + 4);
      float v[8] = {v0.x, v0.y, v0.z, v0.w, v1.x, v1.y, v1.z, v1.w};
      unsigned short h8[8], l8[8];
#pragma unroll
      for (int j = 0; j < 8; ++j) {
        h8[j] = f2bf(v[j]);
        l8[j] = f2bf(v[j] - bf2f(h8[j]));
      }
      *(uint4*)&Ah[srow][skslot] = *(const uint4*)h8;
      *(uint4*)&Al[srow][skslot] = *(const uint4*)l8;
    }
    {
      const uint4 wh = *(const uint4*)(Wt_hi + (size_t)srow * KDIM + kc + skslot);
      const uint4 wl = *(const uint4*)(Wt_lo + (size_t)srow * KDIM + kc + skslot);
      *(uint4*)&Bh[srow][skslot] = wh;
      *(uint4*)&Bl[srow][skslot] = wl;
    }
    __syncthreads();

    const bf16x8 ah = *(const bf16x8*)&Ah[m0 + lc][lr * 8];
    const bf16x8 al = *(const bf16x8*)&Al[m0 + lc][lr * 8];
#pragma unroll
    for (int nf = 0; nf < 4; ++nf) {
      const bf16x8 bh = *(const bf16x8*)&Bh[nf * 16 + lc][lr * 8];
      const bf16x8 bl = *(const bf16x8*)&Bl[nf * 16 + lc][lr * 8];
      acc[nf] = __builtin_amdgcn_mfma_f32_16x16x32_bf16(ah, bh, acc[nf], 0, 0, 0);
      acc[nf] = __builtin_amdgcn_mfma_f32_16x16x32_bf16(ah, bl, acc[nf], 0, 0, 0);
      acc[nf] = __builtin_amdgcn_mfma_f32_16x16x32_bf16(al, bh, acc[nf], 0, 0, 0);
    }
    __syncthreads();
  }

  float as4[4], ad4[4];
#pragma unroll
  for (int nf = 0; nf < 4; ++nf) {
    as4[nf] = a_src[nf * 16 + lc];
    ad4[nf] = a_dst[nf * 16 + lc];
  }
#pragma unroll
  for (int r = 0; r < 4; ++r) {
    const int gn = block_m + m0 + lr * 4 + r;
    float ps = 0.f, pd = 0.f;
#pragma unroll
    for (int nf = 0; nf < 4; ++nf) {
      const float v = acc[nf][r];
      if (gn < N) hb[(size_t)gn * 64 + nf * 16 + lc] = f2bf(v);
      ps += v * as4[nf];
      pd += v * ad4[nf];
    }
#pragma unroll
    for (int off = 1; off < 16; off <<= 1) {
      ps += __shfl_xor(ps, off, 64);
      pd += __shfl_xor(pd, off, 64);
    }
    if (lc == 0 && gn < N) {
      alsrc[gn] = ps;
      aldst[gn] = pd;
    }
  }
}

// ---------------- dense compute (layer 2 gemm, R17 form) ----------------

template <int KDIM>
__global__ __launch_bounds__(256) void gemm_mfma(
    const float* __restrict__ A, const unsigned short* __restrict__ Wt_hi,
    const unsigned short* __restrict__ Wt_lo, unsigned short* __restrict__ hb,
    const float* __restrict__ a_src, const float* __restrict__ a_dst,
    float* __restrict__ alsrc, float* __restrict__ aldst, int N) {
  __shared__ unsigned short Ah[64][40], Al[64][40], Bh[64][40], Bl[64][40];
  const int block_m = blockIdx.x * 64;
  const int t = threadIdx.x;
  const int lane = t & 63;
  const int m0 = (t >> 6) * 16;
  const int lc = lane & 15;
  const int lr = lane >> 4;
  const int srow = t >> 2;
  const int skslot = (t & 3) * 8;

  f32x4 acc[4] = {};

  for (int kc = 0; kc < KDIM; kc += 32) {
    {
      int gn = block_m + srow;
      if (gn >= N) gn = N - 1;
      const float4 v0 = *(const float4*)(A + (size_t)gn * KDIM + kc + skslot);
      const float4 v1 = *(const float4*)(A + (size_t)gn * KDIM + kc + skslot + 4);
      float v[8] = {v0.x, v0.y, v0.z, v0.w, v1.x, v1.y, v1.z, v1.w};
      unsigned short h8[8], l8[8];
#pragma unroll
      for (int j = 0; j < 8; ++j) {
        h8[j] = f2bf(v[j]);
        l8[j] = f2bf(v[j] - bf2f(h8[j]));
      }
      *(uint4*)&Ah[srow][skslot] = *(const uint4*)h8;
      *(uint4*)&Al[srow][skslot] = *(const uint4*)l8;
    }
    {
      const uint4 wh = *(const uint4*)(Wt_hi + (size_t)srow * KDIM + kc + skslot);
      const uint4 wl = *(const uint4*)(Wt_lo + (size_t)srow * KDIM + kc + skslot);
      *(uint4*)&Bh[srow][skslot] = wh;
      *(uint4*)&Bl[srow][skslot] = wl;
    }
    __syncthreads();

    const bf16x8 ah = *(const bf16x8*)&Ah[m0 + lc][lr * 8];
    const bf16x8 al = *(const bf16x8*)&Al[m0 + lc][lr * 8];
#pragma unroll
    for (int nf = 0; nf < 4; ++nf) {
      const bf16x8 bh = *(const bf16x8*)&Bh[nf * 16 + lc][lr * 8];
      const bf16x8 bl = *(const bf16x8*)&Bl[nf * 16 + lc][lr * 8];
      acc[nf] = __builtin_amdgcn_mfma_f32_16x16x32_bf16(ah, bh, acc[nf], 0, 0, 0);
      acc[nf] = __builtin_amdgcn_mfma_f32_16x16x32_bf16(ah, bl, acc[nf], 0, 0, 0);
      acc[nf] = __builtin_amdgcn_mfma_f32_16x16x32_bf16(al, bh, acc[nf], 0, 0, 0);
    }
    __syncthreads();
  }

  float as4[4], ad4[4];
#pragma unroll
  for (int nf = 0; nf < 4; ++nf) {
    as4[nf] = a_src[nf * 16 + lc];
    ad4[nf] = a_dst[nf * 16 + lc];
  }
#pragma unroll
  for (int r = 0; r < 4; ++r) {
    const int gn = block_m + m0 + lr * 4 + r;
    float ps = 0.f, pd = 0.f;
#pragma unroll
    for (int nf = 0; nf < 4; ++nf) {
      const float v = acc[nf][r];
      if (gn < N) hb[(size_t)gn * 64 + nf * 16 + lc] = f2bf(v);
      ps += v * as4[nf];
      pd += v * ad4[nf];
    }
#pragma unroll
    for (int off = 1; off < 16; off <<= 1) {
      ps += __shfl_xor(ps, off, 64);
      pd += __shfl_xor(pd, off, 64);
    }
    if (lc == 0 && gn < N) {
      alsrc[gn] = ps;
      aldst[gn] = pd;
    }
  }
}

// Fused no-max softmax + spmm (R16 hot loop, FROZEN).
// MODE 1: bias+ELU+store rows to outbuf (layer 1 -> h1e).
// MODE 0: bias+ELU, then block-level LDS pre-reduction of the 16 nodes and
//   64 pool atomics per block (post_pool's proven structure, fused into the
//   epilogue; R21's raw-atomic mistake avoided). Requires exact grid
//   (N%16==0) so all threads reach the barriers.
template <int MODE>
__global__ __launch_bounds__(256) void spmm_fused_kernel(
    const int* __restrict__ rowbeg, const int* __restrict__ rowend,
    const int* __restrict__ csrc,
    const float* __restrict__ alsrc, const float* __restrict__ aldst,
    const unsigned short* __restrict__ hb, const float* __restrict__ bias,
    float* __restrict__ outbuf, const int* __restrict__ batch,
    float* __restrict__ pool, int N) {
  __shared__ float red[16][68];
  __shared__ int sB[16];
  __shared__ int uni;
  const int t = threadIdx.x;
  const int l = t & 15;        // slot within group
  const int gb = t & 48;       // group base lane within wave
  const int half = l >> 3;     // which edge of the pair this lane serves
  const int f0 = (l & 7) * 8;  // first feature owned by this lane
  const int node = blockIdx.x * 16 + (t >> 4);
  if (node >= N) return;  // never fires: N%16==0, exact grid
  if (MODE == 0 && t < 16) sB[t] = batch[blockIdx.x * 16 + t];
  const int start = rowbeg[node];
  const int end = rowend[node];
  const float ad = aldst[node];

  float ssum = 0.f;
  float acc[8] = {};

  int i0 = start + l;
  bool v0 = i0 < end;
  int s = v0 ? csrc[i0] : 0;
  float w;
  {
    float e = alsrc[s] + ad;
    e = (e > 0.f) ? e : 0.2f * e;  // leaky_relu 0.2
    w = v0 ? __expf(fminf(e, 80.f)) : 0.f;
  }

  for (int base = start; base < end; base += 16) {
    int in = base + 16 + l;
    bool vn = in < end;
    int sn = vn ? csrc[in] : 0;
    float aln = alsrc[sn];

    uint4 u[8];
#pragma unroll
    for (int j = 0; j < 8; ++j) {
      int sj = __shfl(s, gb + 2 * j + half, 64);
      u[j] = *(const uint4*)(hb + (size_t)sj * 64 + f0);
    }

    ssum += w;
#pragma unroll
    for (int j = 0; j < 8; ++j) {
      float wj = __shfl(w, gb + 2 * j + half, 64);
      acc[0] += wj * __uint_as_float(u[j].x << 16);
      acc[1] += wj * __uint_as_float(u[j].x & 0xFFFF0000u);
      acc[2] += wj * __uint_as_float(u[j].y << 16);
      acc[3] += wj * __uint_as_float(u[j].y & 0xFFFF0000u);
      acc[4] += wj * __uint_as_float(u[j].z << 16);
      acc[5] += wj * __uint_as_float(u[j].z & 0xFFFF0000u);
      acc[6] += wj * __uint_as_float(u[j].w << 16);
      acc[7] += wj * __uint_as_float(u[j].w & 0xFFFF0000u);
    }

    float en = aln + ad;
    en = (en > 0.f) ? en : 0.2f * en;
    w = vn ? __expf(fminf(en, 80.f)) : 0.f;
    s = sn;
  }

#pragma unroll
  for (int k = 0; k < 8; ++k) acc[k] += __shfl_xor(acc[k], 8, 64);
#pragma unroll
  for (int off = 1; off < 16; off <<= 1) ssum += __shfl_xor(ssum, off, 64);

  // bias + ELU applied on half==0 lanes (both modes use bias here)
  float r[8];
  if (half == 0) {
    const float inv = 1.0f / ssum;  // >= 1 edge (self-loop)
#pragma unroll
    for (int k = 0; k < 8; ++k) r[k] = acc[k] * inv;
    const float4 b40 = *(const float4*)(bias + f0);
    const float4 b41 = *(const float4*)(bias + f0 + 4);
    r[0] += b40.x; r[1] += b40.y; r[2] += b40.z; r[3] += b40.w;
    r[4] += b41.x; r[5] += b41.y; r[6] += b41.z; r[7] += b41.w;
#pragma unroll
    for (int k = 0; k < 8; ++k) r[k] = (r[k] > 0.f) ? r[k] : expm1f(r[k]);
  }

  if (MODE == 1) {
    if (half == 0) {
      *(float4*)(outbuf + (size_t)node * 64 + f0) = make_float4(r[0], r[1], r[2], r[3]);
      *(float4*)(outbuf + (size_t)node * 64 + f0 + 4) = make_float4(r[4], r[5], r[6], r[7]);
    }
  } else {
    // block-level pre-reduction (post_pool structure, fused)
    const int g = t >> 4;
    if (half == 0) {
#pragma unroll
      for (int k = 0; k < 8; ++k) red[g][f0 + k] = r[k];
    }
    __syncthreads();
    if (t == 0) {
      int u = 1;
      for (int i = 1; i < 16; i++) u &= (sB[i] == sB[0]);
      uni = u;
    }
    __syncthreads();
    if (t < 64) {
      const float* rf = &red[0][0];  // row stride 68 floats
      if (uni) {
        float sum = 0.f;
#pragma unroll
        for (int n = 0; n < 16; n++) sum += rf[n * 68 + t];
        atomicAdd(&pool[(size_t)sB[0] * 64 + t], sum);
      } else {
        for (int n = 0; n < 16; n++) {
          atomicAdd(&pool[(size_t)sB[n] * 64 + t], rf[n * 68 + t]);
        }
      }
    }
  }
}

// out[g] = (pool[g,:]/cnt[g]) . Wfc + bfc ; cnt from sorted-batch bounds.
__global__ void final_kernel(const float* __restrict__ pool, const int* __restrict__ gstart,
                             const float* __restrict__ Wfc, const float* __restrict__ bfc,
                             float* __restrict__ out, int G) {
  int wid = (blockIdx.x * blockDim.x + threadIdx.x) >> 6;
  int lane = threadIdx.x & 63;
  if (wid >= G) return;
  float c = (float)max(gstart[wid + 1] - gstart[wid], 1);
  float v = pool[(size_t)wid * 64 + lane] * (1.0f / c) * Wfc[lane];
  v = wave_reduce_sum(v);
  if (lane == 0) out[wid] = v + bfc[0];
}

// ---------------------------------------------------------------------------

extern "C" void kernel_launch(void* const* d_in, const int* in_sizes, int n_in,
                              void* d_out, int out_size, void* d_ws, size_t ws_size,
                              hipStream_t stream) {
  const float* x     = (const float*)d_in[0];
  const int*   ei    = (const int*)d_in[1];
  const int*   batch = (const int*)d_in[2];
  const float* W1    = (const float*)d_in[3];
  const float* asrc1 = (const float*)d_in[4];
  const float* adst1 = (const float*)d_in[5];
  const float* b1    = (const float*)d_in[6];
  const float* W2    = (const float*)d_in[7];
  const float* asrc2 = (const float*)d_in[8];
  const float* adst2 = (const float*)d_in[9];
  const float* b2    = (const float*)d_in[10];
  const float* Wfc   = (const float*)d_in[11];
  const float* bfc   = (const float*)d_in[12];
  float* out = (float*)d_out;

  const int N = in_sizes[0] / 128;  // 100000
  const int E = in_sizes[1] / 2;    // 1600000
  const int G = 256;
  const int M = E + N;              // edges incl self-loops
  const int NB = (N + BIN_NODES - 1) >> BIN_SHIFT;  // 782 bins
  const int NPLACE = (M + PLACE_CHUNK - 1) / PLACE_CHUNK;

  // workspace carve (256B aligned)
  char* p = (char*)d_ws;
  auto alloc = [&](size_t bytes) {
    char* r = p;
    p += (bytes + 255) & ~size_t(255);
    return r;
  };
  float*          h1e    = (float*)alloc((size_t)N * 64 * 4);
  unsigned short* hb     = (unsigned short*)alloc((size_t)N * 64 * 2);
  float* alsrc  = (float*)alloc((size_t)N * 4);
  float* aldst  = (float*)alloc((size_t)N * 4);
  int*   rowbeg = (int*)alloc((size_t)N * 4);
  int*   rowend = (int*)alloc((size_t)N * 4);
  int*   csrc   = (int*)alloc((size_t)NB * BIN_CAP * 4);
  unsigned int* binned = (unsigned int*)alloc((size_t)NB * BIN_CAP * 4);
  int*   binCursor = (int*)alloc((size_t)NB * 4);
  float* pool   = (float*)alloc((size_t)G * 64 * 4);
  int*   gstart = (int*)alloc((size_t)(G + 1) * 4);
  unsigned short* w1thi = (unsigned short*)alloc((size_t)64 * 128 * 2);
  unsigned short* w1tlo = (unsigned short*)alloc((size_t)64 * 128 * 2);
  unsigned short* w2thi = (unsigned short*)alloc((size_t)64 * 64 * 2);
  unsigned short* w2tlo = (unsigned short*)alloc((size_t)64 * 64 * 2);

  // ---- stage 1: zero binCursor, then MEGA_A (setup ∪ bin_place) ----
  hipMemsetAsync(binCursor, 0, (size_t)NB * 4, stream);
  mega_a_kernel<<<SETUP_BLOCKS + NPLACE, 256, 0, stream>>>(
      W1, w1thi, w1tlo, W2, w2thi, w2tlo, batch, gstart, pool,
      ei, E, M, NB, binCursor, binned, N, G);

  // ---- stage 2: MEGA_B (finalize ∪ gemm128) ----
  finalize_gemm_kernel<<<NB + (N + 63) / 64, 256, 0, stream>>>(
      binned, binCursor, rowbeg, rowend, csrc, NB,
      x, w1thi, w1tlo, hb, asrc1, adst1, alsrc, aldst, N);

  // ---- layer 1 spmm ----
  spmm_fused_kernel<1><<<(N + 15) / 16, 256, 0, stream>>>(
      rowbeg, rowend, csrc, alsrc, aldst, hb, b1, h1e, nullptr, nullptr, N);

  // ---- layer 2 (pool pre-reduced + accumulated in spmm epilogue) ----
  gemm_mfma<64><<<(N + 63) / 64, 256, 0, stream>>>(h1e, w2thi, w2tlo, hb, asrc2, adst2,
                                                   alsrc, aldst, N);
  spmm_fused_kernel<0><<<(N + 15) / 16, 256, 0, stream>>>(
      rowbeg, rowend, csrc, alsrc, aldst, hb, b2, nullptr, batch, pool, N);

  // ---- readout ----
  final_kernel<<<(G * 64 + 255) / 256, 256, 0, stream>>>(pool, gstart, Wfc, bfc, out, G);
}

// Round 13
// 258.432 us; speedup vs baseline: 1.5227x; 1.0099x over previous
//
#include <hip/hip_runtime.h>
#include <hip/hip_bf16.h>
#include <cstdint>

// ---------------------------------------------------------------------------
// GAT 2-layer model on MI355X.
// R14-R16: spmm gather loop pinned at ~42us: FETCH ~= compulsory per-XCD L2
//   fill of hb (8 x 12.8MB) through the ~2.75TB/s L3->L2 path. Hot loop
//   FROZEN; byte-reduction blocked by precision (bf16 needed).
// R17 (WIN): GEMMs on bf16 MFMA via LDS staging, split precision.
// R18 (REGR): device-wide scatter CSR. Lesson: scatter stays window-confined.
// R19 (REGR): LDS-free gemm. Lesson: barrier-paced staging is load-bearing.
// R20 (WIN): fused setup kernel. R24 (WIN): MEGA_A/MEGA_B co-scheduling.
// R21/R22 (REGR): pool fused as RAW per-wave atomics. Lesson: block-level
//   pre-reduce before device atomics.
// R25 (WIN 264.7->261.0): pool fused into spmm<0> epilogue with LDS
//   pre-reduction: +1.5us kernel, -25MB writes, -1 launch. Confirms:
//   LDS+sync EPILOGUE fusion is safe; R12/R21 failures were divergence /
//   raw atomics, not fusion per se.
// R26: gemm64 fused into spmm<1> epilogue by the same pattern: hot loop
//   byte-identical; epilogue stages the block's 16 fp32 h1 rows as split
//   bf16 into 4.7KB LDS, 1 barrier, 4 waves x 6 MFMAs (same 3-term split
//   math as gemm64), writes hb2 + al2 (fresh buffers -- layer-1 hb/al still
//   being gathered by other blocks). Deletes h1e 51.2MB round-trip, the
//   gemm64 launch, and its ~15us. 7 -> 6 launches.
// ---------------------------------------------------------------------------

#define BIN_SHIFT 7
#define BIN_NODES 128
#define BIN_CAP 3584
#define PLACE_CHUNK 2048
#define SETUP_BLOCKS 114  // 32 wsplitW1 + 16 wsplitW2 + 2 bounds + 64 poolzero

typedef __attribute__((ext_vector_type(8))) short bf16x8;
typedef __attribute__((ext_vector_type(4))) float f32x4;

__device__ __forceinline__ float wave_reduce_sum(float v) {
#pragma unroll
  for (int off = 32; off > 0; off >>= 1) v += __shfl_xor(v, off, 64);
  return v;
}

__device__ __forceinline__ unsigned short f2bf(float f) {  // RNE
  unsigned int u = __float_as_uint(f);
  u += 0x7fffu + ((u >> 16) & 1u);
  return (unsigned short)(u >> 16);
}
__device__ __forceinline__ float bf2f(unsigned short u) {
  return __uint_as_float(((unsigned int)u) << 16);
}

// ---------------- MEGA_A: setup ∪ bin_place ----------------
__global__ __launch_bounds__(256) void mega_a_kernel(
    const float* __restrict__ W1, unsigned short* __restrict__ w1thi,
    unsigned short* __restrict__ w1tlo, const float* __restrict__ W2,
    unsigned short* __restrict__ w2thi, unsigned short* __restrict__ w2tlo,
    const int* __restrict__ batch, int* __restrict__ gstart,
    float* __restrict__ pool, const int* __restrict__ ei, int E, int M,
    int NB, int* __restrict__ binCursor, unsigned int* __restrict__ binned,
    int N, int G) {
  __shared__ int cur[1024];
  __shared__ int res[1024];
  const int b = blockIdx.x;
  const int t = threadIdx.x;

  if (b < 32) {
    int idx = b * 256 + t;  // < 8192 = 128*64
    int n = idx & 63, k = idx >> 6;
    float v = W1[(size_t)k * 64 + n];
    unsigned short h = f2bf(v);
    w1thi[(size_t)n * 128 + k] = h;
    w1tlo[(size_t)n * 128 + k] = f2bf(v - bf2f(h));
    return;
  } else if (b < 48) {
    int idx = (b - 32) * 256 + t;  // < 4096 = 64*64
    int n = idx & 63, k = idx >> 6;
    float v = W2[(size_t)k * 64 + n];
    unsigned short h = f2bf(v);
    w2thi[(size_t)n * 64 + k] = h;
    w2tlo[(size_t)n * 64 + k] = f2bf(v - bf2f(h));
    return;
  } else if (b < 50) {
    int g = (b - 48) * 256 + t;
    if (g <= G) {
      int lo = 0, hi = N;
      while (lo < hi) {
        int mid = (lo + hi) >> 1;
        if (batch[mid] < g) lo = mid + 1;
        else hi = mid;
      }
      gstart[g] = lo;
    }
    return;
  } else if (b < SETUP_BLOCKS) {
    int i = (b - 50) * 256 + t;  // < 16384
    pool[i] = 0.f;
    return;
  }

  // ---- bin_place path ----
  const int cbase = (b - SETUP_BLOCKS) * PLACE_CHUNK;
  for (int i = t; i < NB; i += 256) cur[i] = 0;
  __syncthreads();

  unsigned int pk[PLACE_CHUNK / 256];
  int br[PLACE_CHUNK / 256];
#pragma unroll
  for (int j = 0; j < PLACE_CHUNK / 256; ++j) {
    int i = cbase + t + j * 256;
    if (i < M) {
      int s, d;
      if (i < E) { s = ei[i]; d = ei[E + i]; } else { s = d = i - E; }
      int bb = d >> BIN_SHIFT;
      int r = atomicAdd(&cur[bb], 1);
      pk[j] = ((unsigned int)(d & (BIN_NODES - 1)) << 24) | (unsigned int)s;
      br[j] = (bb << 16) | r;
    } else {
      br[j] = -1;
    }
  }
  __syncthreads();
  for (int i = t; i < NB; i += 256) {
    int c = cur[i];
    res[i] = c ? atomicAdd(&binCursor[i], c) : 0;
  }
  __syncthreads();
#pragma unroll
  for (int j = 0; j < PLACE_CHUNK / 256; ++j) {
    if (br[j] >= 0) {
      int bb = br[j] >> 16;
      int pos = res[bb] + (br[j] & 0xFFFF);
      if (pos < BIN_CAP) binned[(size_t)bb * BIN_CAP + pos] = pk[j];
    }
  }
}

// ---------------- MEGA_B: csr_finalize ∪ gemm128 ----------------
__global__ __launch_bounds__(256) void finalize_gemm_kernel(
    const unsigned int* __restrict__ binned, const int* __restrict__ binCursor,
    int* __restrict__ rowbeg, int* __restrict__ rowend, int* __restrict__ csrc,
    int NB,
    const float* __restrict__ A, const unsigned short* __restrict__ Wt_hi,
    const unsigned short* __restrict__ Wt_lo, unsigned short* __restrict__ hb,
    const float* __restrict__ a_src, const float* __restrict__ a_dst,
    float* __restrict__ alsrc, float* __restrict__ aldst, int N) {
  __shared__ unsigned short Ah[64][40], Al[64][40], Bh[64][40], Bl[64][40];
  const int t = threadIdx.x;

  if (blockIdx.x < NB) {
    // ---- finalize path (256t; cnt/wsum carved from Ah/Bh) ----
    int* cnt = (int*)&Ah[0][0];    // 128 ints
    int* wsum = (int*)&Bh[0][0];   // 2 ints
    const int b = blockIdx.x;
    const int nodeBase = b << BIN_SHIFT;
    const int eBase = b * BIN_CAP;
    const int cntE = binCursor[b];

    if (t < 128) cnt[t] = 0;
    __syncthreads();
    for (int i = t; i < cntE; i += 256) {
      atomicAdd(&cnt[binned[eBase + i] >> 24], 1);
    }
    __syncthreads();
    const int lane = t & 63, wv = t >> 6;
    int v = (t < 128) ? cnt[t] : 0;
    int x = v;
#pragma unroll
    for (int o = 1; o < 64; o <<= 1) {
      int u = __shfl_up(x, o, 64);
      if (lane >= o) x += u;
    }
    if (t < 128 && lane == 63) wsum[wv] = x;
    __syncthreads();
    if (t < 128) {
      const int o = ((wv == 1) ? wsum[0] : 0) + x - v;
      int node = nodeBase + t;
      if (node < N) {
        rowbeg[node] = eBase + o;
        rowend[node] = eBase + o + v;
      }
      cnt[t] = o;  // reuse as cursor
    }
    __syncthreads();
    for (int i = t; i < cntE; i += 256) {
      unsigned int pk = binned[eBase + i];
      int r = atomicAdd(&cnt[pk >> 24], 1);
      csrc[eBase + r] = (int)(pk & 0xFFFFFFu);
    }
    return;
  }

  // ---- gemm128 path (R17 body) ----
  constexpr int KDIM = 128;
  const int block_m = (blockIdx.x - NB) * 64;
  const int lane = t & 63;
  const int m0 = (t >> 6) * 16;
  const int lc = lane & 15;
  const int lr = lane >> 4;
  const int srow = t >> 2;
  const int skslot = (t & 3) * 8;

  f32x4 acc[4] = {};

  for (int kc = 0; kc < KDIM; kc += 32) {
    {
      int gn = block_m + srow;
      if (gn >= N) gn = N - 1;
      const float4 v0 = *(const float4*)(A + (size_t)gn * KDIM + kc + skslot);
      const float4 v1 = *(const float4*)(A + (size_t)gn * KDIM + kc + skslot + 4);
      float v[8] = {v0.x, v0.y, v0.z, v0.w, v1.x, v1.y, v1.z, v1.w};
      unsigned short h8[8], l8[8];
#pragma unroll
      for (int j = 0; j < 8; ++j) {
        h8[j] = f2bf(v[j]);
        l8[j] = f2bf(v[j] - bf2f(h8[j]));
      }
      *(uint4*)&Ah[srow][skslot] = *(const uint4*)h8;
      *(uint4*)&Al[srow][skslot] = *(const uint4*)l8;
    }
    {
      const uint4 wh = *(const uint4*)(Wt_hi + (size_t)srow * KDIM + kc + skslot);
      const uint4 wl = *(const uint4*)(Wt_lo + (size_t)srow * KDIM + kc + skslot);
      *(uint4*)&Bh[srow][skslot] = wh;
      *(uint4*)&Bl[srow][skslot] = wl;
    }
    __syncthreads();

    const bf16x8 ah = *(const bf16x8*)&Ah[m0 + lc][lr * 8];
    const bf16x8 al = *(const bf16x8*)&Al[m0 + lc][lr * 8];
#pragma unroll
    for (int nf = 0; nf < 4; ++nf) {
      const bf16x8 bh = *(const bf16x8*)&Bh[nf * 16 + lc][lr * 8];
      const bf16x8 bl = *(const bf16x8*)&Bl[nf * 16 + lc][lr * 8];
      acc[nf] = __builtin_amdgcn_mfma_f32_16x16x32_bf16(ah, bh, acc[nf], 0, 0, 0);
      acc[nf] = __builtin_amdgcn_mfma_f32_16x16x32_bf16(ah, bl, acc[nf], 0, 0, 0);
      acc[nf] = __builtin_amdgcn_mfma_f32_16x16x32_bf16(al, bh, acc[nf], 0, 0, 0);
    }
    __syncthreads();
  }

  float as4[4], ad4[4];
#pragma unroll
  for (int nf = 0; nf < 4; ++nf) {
    as4[nf] = a_src[nf * 16 + lc];
    ad4[nf] = a_dst[nf * 16 + lc];
  }
#pragma unroll
  for (int r = 0; r < 4; ++r) {
    const int gn = block_m + m0 + lr * 4 + r;
    float ps = 0.f, pd = 0.f;
#pragma unroll
    for (int nf = 0; nf < 4; ++nf) {
      const float v = acc[nf][r];
      if (gn < N) hb[(size_t)gn * 64 + nf * 16 + lc] = f2bf(v);
      ps += v * as4[nf];
      pd += v * ad4[nf];
    }
#pragma unroll
    for (int off = 1; off < 16; off <<= 1) {
      ps += __shfl_xor(ps, off, 64);
      pd += __shfl_xor(pd, off, 64);
    }
    if (lc == 0 && gn < N) {
      alsrc[gn] = ps;
      aldst[gn] = pd;
    }
  }
}

// ---------------- layer 1 spmm + layer 2 gemm (fused) ----------------
// Hot loop = R16 form, FROZEN (byte-identical). Epilogue: bias+ELU in-reg,
// stage 16 h1 rows as split bf16 into LDS, 1 barrier, then 4 waves compute
// h1[16x64] @ W2[64x64] via 6 MFMAs each (identical 3-term split math and
// K-order as the old gemm64 -> numerics preserved). Writes hb2 + al2
// (FRESH buffers: layer-1 hb/al are still gathered by concurrent blocks).
// Grid must be exactly N/16 blocks with N%16==0 (barriers).
__global__ __launch_bounds__(256) void spmm_l1_gemm_kernel(
    const int* __restrict__ rowbeg, const int* __restrict__ rowend,
    const int* __restrict__ csrc,
    const float* __restrict__ alsrc, const float* __restrict__ aldst,
    const unsigned short* __restrict__ hb, const float* __restrict__ bias,
    const unsigned short* __restrict__ w2thi, const unsigned short* __restrict__ w2tlo,
    const float* __restrict__ a_src2, const float* __restrict__ a_dst2,
    unsigned short* __restrict__ hb2, float* __restrict__ alsrc2,
    float* __restrict__ aldst2, int N) {
  __shared__ unsigned short Hh[16][72], Hl[16][72];
  __shared__ float alp[16][2];
  const int t = threadIdx.x;
  const int l = t & 15;        // slot within group
  const int gb = t & 48;       // group base lane within wave
  const int half = l >> 3;     // which edge of the pair this lane serves
  const int f0 = (l & 7) * 8;  // first feature owned by this lane
  const int node = blockIdx.x * 16 + (t >> 4);  // always < N (N%16==0)
  const int start = rowbeg[node];
  const int end = rowend[node];
  const float ad = aldst[node];

  float ssum = 0.f;
  float acc[8] = {};

  int i0 = start + l;
  bool v0 = i0 < end;
  int s = v0 ? csrc[i0] : 0;
  float w;
  {
    float e = alsrc[s] + ad;
    e = (e > 0.f) ? e : 0.2f * e;  // leaky_relu 0.2
    w = v0 ? __expf(fminf(e, 80.f)) : 0.f;
  }

  for (int base = start; base < end; base += 16) {
    int in = base + 16 + l;
    bool vn = in < end;
    int sn = vn ? csrc[in] : 0;
    float aln = alsrc[sn];

    uint4 u[8];
#pragma unroll
    for (int j = 0; j < 8; ++j) {
      int sj = __shfl(s, gb + 2 * j + half, 64);
      u[j] = *(const uint4*)(hb + (size_t)sj * 64 + f0);
    }

    ssum += w;
#pragma unroll
    for (int j = 0; j < 8; ++j) {
      float wj = __shfl(w, gb + 2 * j + half, 64);
      acc[0] += wj * __uint_as_float(u[j].x << 16);
      acc[1] += wj * __uint_as_float(u[j].x & 0xFFFF0000u);
      acc[2] += wj * __uint_as_float(u[j].y << 16);
      acc[3] += wj * __uint_as_float(u[j].y & 0xFFFF0000u);
      acc[4] += wj * __uint_as_float(u[j].z << 16);
      acc[5] += wj * __uint_as_float(u[j].z & 0xFFFF0000u);
      acc[6] += wj * __uint_as_float(u[j].w << 16);
      acc[7] += wj * __uint_as_float(u[j].w & 0xFFFF0000u);
    }

    float en = aln + ad;
    en = (en > 0.f) ? en : 0.2f * en;
    w = vn ? __expf(fminf(en, 80.f)) : 0.f;
    s = sn;
  }

#pragma unroll
  for (int k = 0; k < 8; ++k) acc[k] += __shfl_xor(acc[k], 8, 64);
#pragma unroll
  for (int off = 1; off < 16; off <<= 1) ssum += __shfl_xor(ssum, off, 64);

  // ---- epilogue: bias + ELU (h1 row), stage split bf16 into LDS ----
  if (t < 32) alp[t >> 1][t & 1] = 0.f;
  if (half == 0) {
    const float inv = 1.0f / ssum;  // >= 1 edge (self-loop)
    float r[8];
#pragma unroll
    for (int k = 0; k < 8; ++k) r[k] = acc[k] * inv;
    const float4 b40 = *(const float4*)(bias + f0);
    const float4 b41 = *(const float4*)(bias + f0 + 4);
    r[0] += b40.x; r[1] += b40.y; r[2] += b40.z; r[3] += b40.w;
    r[4] += b41.x; r[5] += b41.y; r[6] += b41.z; r[7] += b41.w;
#pragma unroll
    for (int k = 0; k < 8; ++k) r[k] = (r[k] > 0.f) ? r[k] : expm1f(r[k]);
    unsigned short h8[8], l8[8];
#pragma unroll
    for (int k = 0; k < 8; ++k) {
      h8[k] = f2bf(r[k]);
      l8[k] = f2bf(r[k] - bf2f(h8[k]));
    }
    *(uint4*)&Hh[t >> 4][f0] = *(const uint4*)h8;
    *(uint4*)&Hl[t >> 4][f0] = *(const uint4*)l8;
  }
  __syncthreads();

  // ---- mini-GEMM: h1[16x64] @ W2t[64][64] -> hb2 + al2 ----
  const int lane = t & 63;
  const int lc = lane & 15;
  const int lr = lane >> 4;
  const int nf = t >> 6;  // wave owns cols nf*16..nf*16+15
  f32x4 acc2 = {};
#pragma unroll
  for (int kc = 0; kc < 64; kc += 32) {
    const bf16x8 ah = *(const bf16x8*)&Hh[lc][kc + lr * 8];
    const bf16x8 al8 = *(const bf16x8*)&Hl[lc][kc + lr * 8];
    const size_t boff = (size_t)(nf * 16 + lc) * 64 + kc + lr * 8;
    const bf16x8 bh = *(const bf16x8*)(w2thi + boff);
    const bf16x8 bl = *(const bf16x8*)(w2tlo + boff);
    acc2 = __builtin_amdgcn_mfma_f32_16x16x32_bf16(ah, bh, acc2, 0, 0, 0);
    acc2 = __builtin_amdgcn_mfma_f32_16x16x32_bf16(ah, bl, acc2, 0, 0, 0);
    acc2 = __builtin_amdgcn_mfma_f32_16x16x32_bf16(al8, bh, acc2, 0, 0, 0);
  }

  const float as2 = a_src2[nf * 16 + lc];
  const float ad2 = a_dst2[nf * 16 + lc];
#pragma unroll
  for (int r = 0; r < 4; ++r) {
    const int nrow = lr * 4 + r;
    const int gn = blockIdx.x * 16 + nrow;
    const float v = acc2[r];
    hb2[(size_t)gn * 64 + nf * 16 + lc] = f2bf(v);
    float ps = v * as2, pd = v * ad2;
#pragma unroll
    for (int off = 1; off < 16; off <<= 1) {
      ps += __shfl_xor(ps, off, 64);
      pd += __shfl_xor(pd, off, 64);
    }
    if (lc == 0) {
      atomicAdd(&alp[nrow][0], ps);
      atomicAdd(&alp[nrow][1], pd);
    }
  }
  __syncthreads();
  if (t < 16) {
    alsrc2[blockIdx.x * 16 + t] = alp[t][0];
    aldst2[blockIdx.x * 16 + t] = alp[t][1];
  }
}

// ---------------- layer 2 spmm + pool (R25 proven form) ----------------
__global__ __launch_bounds__(256) void spmm_pool_kernel(
    const int* __restrict__ rowbeg, const int* __restrict__ rowend,
    const int* __restrict__ csrc,
    const float* __restrict__ alsrc, const float* __restrict__ aldst,
    const unsigned short* __restrict__ hb, const float* __restrict__ bias,
    const int* __restrict__ batch, float* __restrict__ pool, int N) {
  __shared__ float red[16][68];
  __shared__ int sB[16];
  __shared__ int uni;
  const int t = threadIdx.x;
  const int l = t & 15;
  const int gb = t & 48;
  const int half = l >> 3;
  const int f0 = (l & 7) * 8;
  const int node = blockIdx.x * 16 + (t >> 4);  // always < N (N%16==0)
  if (t < 16) sB[t] = batch[blockIdx.x * 16 + t];
  const int start = rowbeg[node];
  const int end = rowend[node];
  const float ad = aldst[node];

  float ssum = 0.f;
  float acc[8] = {};

  int i0 = start + l;
  bool v0 = i0 < end;
  int s = v0 ? csrc[i0] : 0;
  float w;
  {
    float e = alsrc[s] + ad;
    e = (e > 0.f) ? e : 0.2f * e;  // leaky_relu 0.2
    w = v0 ? __expf(fminf(e, 80.f)) : 0.f;
  }

  for (int base = start; base < end; base += 16) {
    int in = base + 16 + l;
    bool vn = in < end;
    int sn = vn ? csrc[in] : 0;
    float aln = alsrc[sn];

    uint4 u[8];
#pragma unroll
    for (int j = 0; j < 8; ++j) {
      int sj = __shfl(s, gb + 2 * j + half, 64);
      u[j] = *(const uint4*)(hb + (size_t)sj * 64 + f0);
    }

    ssum += w;
#pragma unroll
    for (int j = 0; j < 8; ++j) {
      float wj = __shfl(w, gb + 2 * j + half, 64);
      acc[0] += wj * __uint_as_float(u[j].x << 16);
      acc[1] += wj * __uint_as_float(u[j].x & 0xFFFF0000u);
      acc[2] += wj * __uint_as_float(u[j].y << 16);
      acc[3] += wj * __uint_as_float(u[j].y & 0xFFFF0000u);
      acc[4] += wj * __uint_as_float(u[j].z << 16);
      acc[5] += wj * __uint_as_float(u[j].z & 0xFFFF0000u);
      acc[6] += wj * __uint_as_float(u[j].w << 16);
      acc[7] += wj * __uint_as_float(u[j].w & 0xFFFF0000u);
    }

    float en = aln + ad;
    en = (en > 0.f) ? en : 0.2f * en;
    w = vn ? __expf(fminf(en, 80.f)) : 0.f;
    s = sn;
  }

#pragma unroll
  for (int k = 0; k < 8; ++k) acc[k] += __shfl_xor(acc[k], 8, 64);
#pragma unroll
  for (int off = 1; off < 16; off <<= 1) ssum += __shfl_xor(ssum, off, 64);

  float r[8];
  if (half == 0) {
    const float inv = 1.0f / ssum;
#pragma unroll
    for (int k = 0; k < 8; ++k) r[k] = acc[k] * inv;
    const float4 b40 = *(const float4*)(bias + f0);
    const float4 b41 = *(const float4*)(bias + f0 + 4);
    r[0] += b40.x; r[1] += b40.y; r[2] += b40.z; r[3] += b40.w;
    r[4] += b41.x; r[5] += b41.y; r[6] += b41.z; r[7] += b41.w;
#pragma unroll
    for (int k = 0; k < 8; ++k) r[k] = (r[k] > 0.f) ? r[k] : expm1f(r[k]);
    const int g = t >> 4;
#pragma unroll
    for (int k = 0; k < 8; ++k) red[g][f0 + k] = r[k];
  }
  __syncthreads();
  if (t == 0) {
    int u = 1;
    for (int i = 1; i < 16; i++) u &= (sB[i] == sB[0]);
    uni = u;
  }
  __syncthreads();
  if (t < 64) {
    const float* rf = &red[0][0];  // row stride 68 floats
    if (uni) {
      float sum = 0.f;
#pragma unroll
      for (int n = 0; n < 16; n++) sum += rf[n * 68 + t];
      atomicAdd(&pool[(size_t)sB[0] * 64 + t], sum);
    } else {
      for (int n = 0; n < 16; n++) {
        atomicAdd(&pool[(size_t)sB[n] * 64 + t], rf[n * 68 + t]);
      }
    }
  }
}

// out[g] = (pool[g,:]/cnt[g]) . Wfc + bfc ; cnt from sorted-batch bounds.
__global__ void final_kernel(const float* __restrict__ pool, const int* __restrict__ gstart,
                             const float* __restrict__ Wfc, const float* __restrict__ bfc,
                             float* __restrict__ out, int G) {
  int wid = (blockIdx.x * blockDim.x + threadIdx.x) >> 6;
  int lane = threadIdx.x & 63;
  if (wid >= G) return;
  float c = (float)max(gstart[wid + 1] - gstart[wid], 1);
  float v = pool[(size_t)wid * 64 + lane] * (1.0f / c) * Wfc[lane];
  v = wave_reduce_sum(v);
  if (lane == 0) out[wid] = v + bfc[0];
}

// ---------------------------------------------------------------------------

extern "C" void kernel_launch(void* const* d_in, const int* in_sizes, int n_in,
                              void* d_out, int out_size, void* d_ws, size_t ws_size,
                              hipStream_t stream) {
  const float* x     = (const float*)d_in[0];
  const int*   ei    = (const int*)d_in[1];
  const int*   batch = (const int*)d_in[2];
  const float* W1    = (const float*)d_in[3];
  const float* asrc1 = (const float*)d_in[4];
  const float* adst1 = (const float*)d_in[5];
  const float* b1    = (const float*)d_in[6];
  const float* W2    = (const float*)d_in[7];
  const float* asrc2 = (const float*)d_in[8];
  const float* adst2 = (const float*)d_in[9];
  const float* b2    = (const float*)d_in[10];
  const float* Wfc   = (const float*)d_in[11];
  const float* bfc   = (const float*)d_in[12];
  float* out = (float*)d_out;

  const int N = in_sizes[0] / 128;  // 100000
  const int E = in_sizes[1] / 2;    // 1600000
  const int G = 256;
  const int M = E + N;              // edges incl self-loops
  const int NB = (N + BIN_NODES - 1) >> BIN_SHIFT;  // 782 bins
  const int NPLACE = (M + PLACE_CHUNK - 1) / PLACE_CHUNK;

  // workspace carve (256B aligned)
  char* p = (char*)d_ws;
  auto alloc = [&](size_t bytes) {
    char* r = p;
    p += (bytes + 255) & ~size_t(255);
    return r;
  };
  unsigned short* hb     = (unsigned short*)alloc((size_t)N * 64 * 2);
  unsigned short* hb2    = (unsigned short*)alloc((size_t)N * 64 * 2);
  float* alsrc  = (float*)alloc((size_t)N * 4);
  float* aldst  = (float*)alloc((size_t)N * 4);
  float* alsrc2 = (float*)alloc((size_t)N * 4);
  float* aldst2 = (float*)alloc((size_t)N * 4);
  int*   rowbeg = (int*)alloc((size_t)N * 4);
  int*   rowend = (int*)alloc((size_t)N * 4);
  int*   csrc   = (int*)alloc((size_t)NB * BIN_CAP * 4);
  unsigned int* binned = (unsigned int*)alloc((size_t)NB * BIN_CAP * 4);
  int*   binCursor = (int*)alloc((size_t)NB * 4);
  float* pool   = (float*)alloc((size_t)G * 64 * 4);
  int*   gstart = (int*)alloc((size_t)(G + 1) * 4);
  unsigned short* w1thi = (unsigned short*)alloc((size_t)64 * 128 * 2);
  unsigned short* w1tlo = (unsigned short*)alloc((size_t)64 * 128 * 2);
  unsigned short* w2thi = (unsigned short*)alloc((size_t)64 * 64 * 2);
  unsigned short* w2tlo = (unsigned short*)alloc((size_t)64 * 64 * 2);

  // ---- stage 1: zero binCursor, then MEGA_A (setup ∪ bin_place) ----
  hipMemsetAsync(binCursor, 0, (size_t)NB * 4, stream);
  mega_a_kernel<<<SETUP_BLOCKS + NPLACE, 256, 0, stream>>>(
      W1, w1thi, w1tlo, W2, w2thi, w2tlo, batch, gstart, pool,
      ei, E, M, NB, binCursor, binned, N, G);

  // ---- stage 2: MEGA_B (finalize ∪ gemm128) ----
  finalize_gemm_kernel<<<NB + (N + 63) / 64, 256, 0, stream>>>(
      binned, binCursor, rowbeg, rowend, csrc, NB,
      x, w1thi, w1tlo, hb, asrc1, adst1, alsrc, aldst, N);

  // ---- layer 1 spmm + layer 2 gemm (fused) ----
  spmm_l1_gemm_kernel<<<N / 16, 256, 0, stream>>>(
      rowbeg, rowend, csrc, alsrc, aldst, hb, b1,
      w2thi, w2tlo, asrc2, adst2, hb2, alsrc2, aldst2, N);

  // ---- layer 2 spmm + pool ----
  spmm_pool_kernel<<<N / 16, 256, 0, stream>>>(
      rowbeg, rowend, csrc, alsrc2, aldst2, hb2, b2, batch, pool, N);

  // ---- readout ----
  final_kernel<<<(G * 64 + 255) / 256, 256, 0, stream>>>(pool, gstart, Wfc, bfc, out, G);
}

// Round 14
// 251.993 us; speedup vs baseline: 1.5616x; 1.0256x over previous
//
#include <hip/hip_runtime.h>
#include <hip/hip_bf16.h>
#include <cstdint>

// ---------------------------------------------------------------------------
// GAT 2-layer model on MI355X.
// R14-R16: spmm gather loop pinned at ~42us: FETCH ~= compulsory per-XCD L2
//   fill of hb (8 x 12.8MB). Hot loop FROZEN.
// R17 (WIN): GEMMs on bf16 MFMA via LDS staging, split precision.
// R18 (REGR): device-wide scatter CSR. Lesson: scatter stays window-confined.
// R19 (REGR): LDS-free gemm. Lesson: barrier-paced staging is load-bearing.
// R20/R24 (WIN): setup fusion; MEGA_A/MEGA_B co-scheduling.
// R21/R22 (REGR): raw per-wave pool atomics. Lesson: block-level pre-reduce.
// R25 (WIN): pool fused into spmm<0> epilogue w/ LDS pre-reduction.
// R26 (WIN 261.0->258.4): gemm64 fused into spmm<1> epilogue (mini-MFMA on
//   the block's 16 h1 rows); h1e 51MB round-trip + launch deleted. Fused
//   kernel 55.5us (+13.2 vs frozen loop) -> epilogue overhead too high.
// R27: epilogue de-bottlenecked: (a) W2 fragment loads hoisted ABOVE the
//   staging phase (latency hides under bias/ELU/split + barrier, instead of
//   sitting cold on the critical path after it); (b) al reduction made
//   atomic-free: per-wave slots alp[4][16][2] + 16-thread sum (was 128 LDS
//   atomics/block). Math and K-order identical -> numerics unchanged.
// ---------------------------------------------------------------------------

#define BIN_SHIFT 7
#define BIN_NODES 128
#define BIN_CAP 3584
#define PLACE_CHUNK 2048
#define SETUP_BLOCKS 114  // 32 wsplitW1 + 16 wsplitW2 + 2 bounds + 64 poolzero

typedef __attribute__((ext_vector_type(8))) short bf16x8;
typedef __attribute__((ext_vector_type(4))) float f32x4;

__device__ __forceinline__ float wave_reduce_sum(float v) {
#pragma unroll
  for (int off = 32; off > 0; off >>= 1) v += __shfl_xor(v, off, 64);
  return v;
}

__device__ __forceinline__ unsigned short f2bf(float f) {  // RNE
  unsigned int u = __float_as_uint(f);
  u += 0x7fffu + ((u >> 16) & 1u);
  return (unsigned short)(u >> 16);
}
__device__ __forceinline__ float bf2f(unsigned short u) {
  return __uint_as_float(((unsigned int)u) << 16);
}

// ---------------- MEGA_A: setup ∪ bin_place ----------------
__global__ __launch_bounds__(256) void mega_a_kernel(
    const float* __restrict__ W1, unsigned short* __restrict__ w1thi,
    unsigned short* __restrict__ w1tlo, const float* __restrict__ W2,
    unsigned short* __restrict__ w2thi, unsigned short* __restrict__ w2tlo,
    const int* __restrict__ batch, int* __restrict__ gstart,
    float* __restrict__ pool, const int* __restrict__ ei, int E, int M,
    int NB, int* __restrict__ binCursor, unsigned int* __restrict__ binned,
    int N, int G) {
  __shared__ int cur[1024];
  __shared__ int res[1024];
  const int b = blockIdx.x;
  const int t = threadIdx.x;

  if (b < 32) {
    int idx = b * 256 + t;  // < 8192 = 128*64
    int n = idx & 63, k = idx >> 6;
    float v = W1[(size_t)k * 64 + n];
    unsigned short h = f2bf(v);
    w1thi[(size_t)n * 128 + k] = h;
    w1tlo[(size_t)n * 128 + k] = f2bf(v - bf2f(h));
    return;
  } else if (b < 48) {
    int idx = (b - 32) * 256 + t;  // < 4096 = 64*64
    int n = idx & 63, k = idx >> 6;
    float v = W2[(size_t)k * 64 + n];
    unsigned short h = f2bf(v);
    w2thi[(size_t)n * 64 + k] = h;
    w2tlo[(size_t)n * 64 + k] = f2bf(v - bf2f(h));
    return;
  } else if (b < 50) {
    int g = (b - 48) * 256 + t;
    if (g <= G) {
      int lo = 0, hi = N;
      while (lo < hi) {
        int mid = (lo + hi) >> 1;
        if (batch[mid] < g) lo = mid + 1;
        else hi = mid;
      }
      gstart[g] = lo;
    }
    return;
  } else if (b < SETUP_BLOCKS) {
    int i = (b - 50) * 256 + t;  // < 16384
    pool[i] = 0.f;
    return;
  }

  // ---- bin_place path ----
  const int cbase = (b - SETUP_BLOCKS) * PLACE_CHUNK;
  for (int i = t; i < NB; i += 256) cur[i] = 0;
  __syncthreads();

  unsigned int pk[PLACE_CHUNK / 256];
  int br[PLACE_CHUNK / 256];
#pragma unroll
  for (int j = 0; j < PLACE_CHUNK / 256; ++j) {
    int i = cbase + t + j * 256;
    if (i < M) {
      int s, d;
      if (i < E) { s = ei[i]; d = ei[E + i]; } else { s = d = i - E; }
      int bb = d >> BIN_SHIFT;
      int r = atomicAdd(&cur[bb], 1);
      pk[j] = ((unsigned int)(d & (BIN_NODES - 1)) << 24) | (unsigned int)s;
      br[j] = (bb << 16) | r;
    } else {
      br[j] = -1;
    }
  }
  __syncthreads();
  for (int i = t; i < NB; i += 256) {
    int c = cur[i];
    res[i] = c ? atomicAdd(&binCursor[i], c) : 0;
  }
  __syncthreads();
#pragma unroll
  for (int j = 0; j < PLACE_CHUNK / 256; ++j) {
    if (br[j] >= 0) {
      int bb = br[j] >> 16;
      int pos = res[bb] + (br[j] & 0xFFFF);
      if (pos < BIN_CAP) binned[(size_t)bb * BIN_CAP + pos] = pk[j];
    }
  }
}

// ---------------- MEGA_B: csr_finalize ∪ gemm128 ----------------
__global__ __launch_bounds__(256) void finalize_gemm_kernel(
    const unsigned int* __restrict__ binned, const int* __restrict__ binCursor,
    int* __restrict__ rowbeg, int* __restrict__ rowend, int* __restrict__ csrc,
    int NB,
    const float* __restrict__ A, const unsigned short* __restrict__ Wt_hi,
    const unsigned short* __restrict__ Wt_lo, unsigned short* __restrict__ hb,
    const float* __restrict__ a_src, const float* __restrict__ a_dst,
    float* __restrict__ alsrc, float* __restrict__ aldst, int N) {
  __shared__ unsigned short Ah[64][40], Al[64][40], Bh[64][40], Bl[64][40];
  const int t = threadIdx.x;

  if (blockIdx.x < NB) {
    // ---- finalize path (256t; cnt/wsum carved from Ah/Bh) ----
    int* cnt = (int*)&Ah[0][0];    // 128 ints
    int* wsum = (int*)&Bh[0][0];   // 2 ints
    const int b = blockIdx.x;
    const int nodeBase = b << BIN_SHIFT;
    const int eBase = b * BIN_CAP;
    const int cntE = binCursor[b];

    if (t < 128) cnt[t] = 0;
    __syncthreads();
    for (int i = t; i < cntE; i += 256) {
      atomicAdd(&cnt[binned[eBase + i] >> 24], 1);
    }
    __syncthreads();
    const int lane = t & 63, wv = t >> 6;
    int v = (t < 128) ? cnt[t] : 0;
    int x = v;
#pragma unroll
    for (int o = 1; o < 64; o <<= 1) {
      int u = __shfl_up(x, o, 64);
      if (lane >= o) x += u;
    }
    if (t < 128 && lane == 63) wsum[wv] = x;
    __syncthreads();
    if (t < 128) {
      const int o = ((wv == 1) ? wsum[0] : 0) + x - v;
      int node = nodeBase + t;
      if (node < N) {
        rowbeg[node] = eBase + o;
        rowend[node] = eBase + o + v;
      }
      cnt[t] = o;  // reuse as cursor
    }
    __syncthreads();
    for (int i = t; i < cntE; i += 256) {
      unsigned int pk = binned[eBase + i];
      int r = atomicAdd(&cnt[pk >> 24], 1);
      csrc[eBase + r] = (int)(pk & 0xFFFFFFu);
    }
    return;
  }

  // ---- gemm128 path (R17 body) ----
  constexpr int KDIM = 128;
  const int block_m = (blockIdx.x - NB) * 64;
  const int lane = t & 63;
  const int m0 = (t >> 6) * 16;
  const int lc = lane & 15;
  const int lr = lane >> 4;
  const int srow = t >> 2;
  const int skslot = (t & 3) * 8;

  f32x4 acc[4] = {};

  for (int kc = 0; kc < KDIM; kc += 32) {
    {
      int gn = block_m + srow;
      if (gn >= N) gn = N - 1;
      const float4 v0 = *(const float4*)(A + (size_t)gn * KDIM + kc + skslot);
      const float4 v1 = *(const float4*)(A + (size_t)gn * KDIM + kc + skslot + 4);
      float v[8] = {v0.x, v0.y, v0.z, v0.w, v1.x, v1.y, v1.z, v1.w};
      unsigned short h8[8], l8[8];
#pragma unroll
      for (int j = 0; j < 8; ++j) {
        h8[j] = f2bf(v[j]);
        l8[j] = f2bf(v[j] - bf2f(h8[j]));
      }
      *(uint4*)&Ah[srow][skslot] = *(const uint4*)h8;
      *(uint4*)&Al[srow][skslot] = *(const uint4*)l8;
    }
    {
      const uint4 wh = *(const uint4*)(Wt_hi + (size_t)srow * KDIM + kc + skslot);
      const uint4 wl = *(const uint4*)(Wt_lo + (size_t)srow * KDIM + kc + skslot);
      *(uint4*)&Bh[srow][skslot] = wh;
      *(uint4*)&Bl[srow][skslot] = wl;
    }
    __syncthreads();

    const bf16x8 ah = *(const bf16x8*)&Ah[m0 + lc][lr * 8];
    const bf16x8 al = *(const bf16x8*)&Al[m0 + lc][lr * 8];
#pragma unroll
    for (int nf = 0; nf < 4; ++nf) {
      const bf16x8 bh = *(const bf16x8*)&Bh[nf * 16 + lc][lr * 8];
      const bf16x8 bl = *(const bf16x8*)&Bl[nf * 16 + lc][lr * 8];
      acc[nf] = __builtin_amdgcn_mfma_f32_16x16x32_bf16(ah, bh, acc[nf], 0, 0, 0);
      acc[nf] = __builtin_amdgcn_mfma_f32_16x16x32_bf16(ah, bl, acc[nf], 0, 0, 0);
      acc[nf] = __builtin_amdgcn_mfma_f32_16x16x32_bf16(al, bh, acc[nf], 0, 0, 0);
    }
    __syncthreads();
  }

  float as4[4], ad4[4];
#pragma unroll
  for (int nf = 0; nf < 4; ++nf) {
    as4[nf] = a_src[nf * 16 + lc];
    ad4[nf] = a_dst[nf * 16 + lc];
  }
#pragma unroll
  for (int r = 0; r < 4; ++r) {
    const int gn = block_m + m0 + lr * 4 + r;
    float ps = 0.f, pd = 0.f;
#pragma unroll
    for (int nf = 0; nf < 4; ++nf) {
      const float v = acc[nf][r];
      if (gn < N) hb[(size_t)gn * 64 + nf * 16 + lc] = f2bf(v);
      ps += v * as4[nf];
      pd += v * ad4[nf];
    }
#pragma unroll
    for (int off = 1; off < 16; off <<= 1) {
      ps += __shfl_xor(ps, off, 64);
      pd += __shfl_xor(pd, off, 64);
    }
    if (lc == 0 && gn < N) {
      alsrc[gn] = ps;
      aldst[gn] = pd;
    }
  }
}

// ---------------- layer 1 spmm + layer 2 gemm (fused) ----------------
// Hot loop = R16 form, FROZEN (byte-identical). Epilogue (R27 form):
// W2 fragments loaded FIRST (latency hides under bias/ELU/split + barrier),
// then stage split-bf16 h1 rows to LDS, barrier, 6 MFMAs per wave (same
// 3-term split math and K-order as gemm64), atomic-free al reduction via
// per-wave slots. Writes hb2 + al2 (fresh buffers). Grid exactly N/16.
__global__ __launch_bounds__(256) void spmm_l1_gemm_kernel(
    const int* __restrict__ rowbeg, const int* __restrict__ rowend,
    const int* __restrict__ csrc,
    const float* __restrict__ alsrc, const float* __restrict__ aldst,
    const unsigned short* __restrict__ hb, const float* __restrict__ bias,
    const unsigned short* __restrict__ w2thi, const unsigned short* __restrict__ w2tlo,
    const float* __restrict__ a_src2, const float* __restrict__ a_dst2,
    unsigned short* __restrict__ hb2, float* __restrict__ alsrc2,
    float* __restrict__ aldst2, int N) {
  __shared__ unsigned short Hh[16][72], Hl[16][72];
  __shared__ float alp[4][16][2];
  const int t = threadIdx.x;
  const int l = t & 15;        // slot within group
  const int gb = t & 48;       // group base lane within wave
  const int half = l >> 3;     // which edge of the pair this lane serves
  const int f0 = (l & 7) * 8;  // first feature owned by this lane
  const int node = blockIdx.x * 16 + (t >> 4);  // always < N (N%16==0)
  const int start = rowbeg[node];
  const int end = rowend[node];
  const float ad = aldst[node];

  float ssum = 0.f;
  float acc[8] = {};

  int i0 = start + l;
  bool v0 = i0 < end;
  int s = v0 ? csrc[i0] : 0;
  float w;
  {
    float e = alsrc[s] + ad;
    e = (e > 0.f) ? e : 0.2f * e;  // leaky_relu 0.2
    w = v0 ? __expf(fminf(e, 80.f)) : 0.f;
  }

  for (int base = start; base < end; base += 16) {
    int in = base + 16 + l;
    bool vn = in < end;
    int sn = vn ? csrc[in] : 0;
    float aln = alsrc[sn];

    uint4 u[8];
#pragma unroll
    for (int j = 0; j < 8; ++j) {
      int sj = __shfl(s, gb + 2 * j + half, 64);
      u[j] = *(const uint4*)(hb + (size_t)sj * 64 + f0);
    }

    ssum += w;
#pragma unroll
    for (int j = 0; j < 8; ++j) {
      float wj = __shfl(w, gb + 2 * j + half, 64);
      acc[0] += wj * __uint_as_float(u[j].x << 16);
      acc[1] += wj * __uint_as_float(u[j].x & 0xFFFF0000u);
      acc[2] += wj * __uint_as_float(u[j].y << 16);
      acc[3] += wj * __uint_as_float(u[j].y & 0xFFFF0000u);
      acc[4] += wj * __uint_as_float(u[j].z << 16);
      acc[5] += wj * __uint_as_float(u[j].z & 0xFFFF0000u);
      acc[6] += wj * __uint_as_float(u[j].w << 16);
      acc[7] += wj * __uint_as_float(u[j].w & 0xFFFF0000u);
    }

    float en = aln + ad;
    en = (en > 0.f) ? en : 0.2f * en;
    w = vn ? __expf(fminf(en, 80.f)) : 0.f;
    s = sn;
  }

#pragma unroll
  for (int k = 0; k < 8; ++k) acc[k] += __shfl_xor(acc[k], 8, 64);
#pragma unroll
  for (int off = 1; off < 16; off <<= 1) ssum += __shfl_xor(ssum, off, 64);

  // ---- epilogue ----
  // (a) W2 fragment loads FIRST: depend only on lane; latency hides under
  // the bias/ELU/split VALU work and the staging barrier below.
  const int lane = t & 63;
  const int lc2 = lane & 15;
  const int lr2 = lane >> 4;
  const int nf = t >> 6;  // wave owns cols nf*16..nf*16+15
  const size_t boff0 = (size_t)(nf * 16 + lc2) * 64 + lr2 * 8;
  const size_t boff1 = boff0 + 32;
  const bf16x8 bh0 = *(const bf16x8*)(w2thi + boff0);
  const bf16x8 bl0 = *(const bf16x8*)(w2tlo + boff0);
  const bf16x8 bh1 = *(const bf16x8*)(w2thi + boff1);
  const bf16x8 bl1 = *(const bf16x8*)(w2tlo + boff1);
  const float as2 = a_src2[nf * 16 + lc2];
  const float ad2 = a_dst2[nf * 16 + lc2];

  // (b) bias + ELU (h1 row), stage split bf16 into LDS
  if (half == 0) {
    const float inv = 1.0f / ssum;  // >= 1 edge (self-loop)
    float r[8];
#pragma unroll
    for (int k = 0; k < 8; ++k) r[k] = acc[k] * inv;
    const float4 b40 = *(const float4*)(bias + f0);
    const float4 b41 = *(const float4*)(bias + f0 + 4);
    r[0] += b40.x; r[1] += b40.y; r[2] += b40.z; r[3] += b40.w;
    r[4] += b41.x; r[5] += b41.y; r[6] += b41.z; r[7] += b41.w;
#pragma unroll
    for (int k = 0; k < 8; ++k) r[k] = (r[k] > 0.f) ? r[k] : expm1f(r[k]);
    unsigned short h8[8], l8[8];
#pragma unroll
    for (int k = 0; k < 8; ++k) {
      h8[k] = f2bf(r[k]);
      l8[k] = f2bf(r[k] - bf2f(h8[k]));
    }
    *(uint4*)&Hh[t >> 4][f0] = *(const uint4*)h8;
    *(uint4*)&Hl[t >> 4][f0] = *(const uint4*)l8;
  }
  __syncthreads();

  // (c) mini-GEMM: h1[16x64] @ W2t[64][64] -> hb2 + al2 (same K-order)
  f32x4 acc2 = {};
  {
    const bf16x8 ah0 = *(const bf16x8*)&Hh[lc2][lr2 * 8];
    const bf16x8 al0 = *(const bf16x8*)&Hl[lc2][lr2 * 8];
    acc2 = __builtin_amdgcn_mfma_f32_16x16x32_bf16(ah0, bh0, acc2, 0, 0, 0);
    acc2 = __builtin_amdgcn_mfma_f32_16x16x32_bf16(ah0, bl0, acc2, 0, 0, 0);
    acc2 = __builtin_amdgcn_mfma_f32_16x16x32_bf16(al0, bh0, acc2, 0, 0, 0);
    const bf16x8 ah1 = *(const bf16x8*)&Hh[lc2][32 + lr2 * 8];
    const bf16x8 al1 = *(const bf16x8*)&Hl[lc2][32 + lr2 * 8];
    acc2 = __builtin_amdgcn_mfma_f32_16x16x32_bf16(ah1, bh1, acc2, 0, 0, 0);
    acc2 = __builtin_amdgcn_mfma_f32_16x16x32_bf16(ah1, bl1, acc2, 0, 0, 0);
    acc2 = __builtin_amdgcn_mfma_f32_16x16x32_bf16(al1, bh1, acc2, 0, 0, 0);
  }

  // (d) hb2 write + atomic-free al reduction (per-wave slots)
  float psl[4], pdl[4];
#pragma unroll
  for (int r = 0; r < 4; ++r) {
    const int nrow = lr2 * 4 + r;
    const int gn = blockIdx.x * 16 + nrow;
    const float v = acc2[r];
    hb2[(size_t)gn * 64 + nf * 16 + lc2] = f2bf(v);
    float ps = v * as2, pd = v * ad2;
#pragma unroll
    for (int off = 1; off < 16; off <<= 1) {
      ps += __shfl_xor(ps, off, 64);
      pd += __shfl_xor(pd, off, 64);
    }
    psl[r] = ps;
    pdl[r] = pd;
  }
  if (lc2 == 0) {
#pragma unroll
    for (int r = 0; r < 4; ++r) {
      alp[nf][lr2 * 4 + r][0] = psl[r];
      alp[nf][lr2 * 4 + r][1] = pdl[r];
    }
  }
  __syncthreads();
  if (t < 16) {
    alsrc2[blockIdx.x * 16 + t] = alp[0][t][0] + alp[1][t][0] + alp[2][t][0] + alp[3][t][0];
    aldst2[blockIdx.x * 16 + t] = alp[0][t][1] + alp[1][t][1] + alp[2][t][1] + alp[3][t][1];
  }
}

// ---------------- layer 2 spmm + pool (R25 proven form) ----------------
__global__ __launch_bounds__(256) void spmm_pool_kernel(
    const int* __restrict__ rowbeg, const int* __restrict__ rowend,
    const int* __restrict__ csrc,
    const float* __restrict__ alsrc, const float* __restrict__ aldst,
    const unsigned short* __restrict__ hb, const float* __restrict__ bias,
    const int* __restrict__ batch, float* __restrict__ pool, int N) {
  __shared__ float red[16][68];
  __shared__ int sB[16];
  __shared__ int uni;
  const int t = threadIdx.x;
  const int l = t & 15;
  const int gb = t & 48;
  const int half = l >> 3;
  const int f0 = (l & 7) * 8;
  const int node = blockIdx.x * 16 + (t >> 4);  // always < N (N%16==0)
  if (t < 16) sB[t] = batch[blockIdx.x * 16 + t];
  const int start = rowbeg[node];
  const int end = rowend[node];
  const float ad = aldst[node];

  float ssum = 0.f;
  float acc[8] = {};

  int i0 = start + l;
  bool v0 = i0 < end;
  int s = v0 ? csrc[i0] : 0;
  float w;
  {
    float e = alsrc[s] + ad;
    e = (e > 0.f) ? e : 0.2f * e;  // leaky_relu 0.2
    w = v0 ? __expf(fminf(e, 80.f)) : 0.f;
  }

  for (int base = start; base < end; base += 16) {
    int in = base + 16 + l;
    bool vn = in < end;
    int sn = vn ? csrc[in] : 0;
    float aln = alsrc[sn];

    uint4 u[8];
#pragma unroll
    for (int j = 0; j < 8; ++j) {
      int sj = __shfl(s, gb + 2 * j + half, 64);
      u[j] = *(const uint4*)(hb + (size_t)sj * 64 + f0);
    }

    ssum += w;
#pragma unroll
    for (int j = 0; j < 8; ++j) {
      float wj = __shfl(w, gb + 2 * j + half, 64);
      acc[0] += wj * __uint_as_float(u[j].x << 16);
      acc[1] += wj * __uint_as_float(u[j].x & 0xFFFF0000u);
      acc[2] += wj * __uint_as_float(u[j].y << 16);
      acc[3] += wj * __uint_as_float(u[j].y & 0xFFFF0000u);
      acc[4] += wj * __uint_as_float(u[j].z << 16);
      acc[5] += wj * __uint_as_float(u[j].z & 0xFFFF0000u);
      acc[6] += wj * __uint_as_float(u[j].w << 16);
      acc[7] += wj * __uint_as_float(u[j].w & 0xFFFF0000u);
    }

    float en = aln + ad;
    en = (en > 0.f) ? en : 0.2f * en;
    w = vn ? __expf(fminf(en, 80.f)) : 0.f;
    s = sn;
  }

#pragma unroll
  for (int k = 0; k < 8; ++k) acc[k] += __shfl_xor(acc[k], 8, 64);
#pragma unroll
  for (int off = 1; off < 16; off <<= 1) ssum += __shfl_xor(ssum, off, 64);

  float r[8];
  if (half == 0) {
    const float inv = 1.0f / ssum;
#pragma unroll
    for (int k = 0; k < 8; ++k) r[k] = acc[k] * inv;
    const float4 b40 = *(const float4*)(bias + f0);
    const float4 b41 = *(const float4*)(bias + f0 + 4);
    r[0] += b40.x; r[1] += b40.y; r[2] += b40.z; r[3] += b40.w;
    r[4] += b41.x; r[5] += b41.y; r[6] += b41.z; r[7] += b41.w;
#pragma unroll
    for (int k = 0; k < 8; ++k) r[k] = (r[k] > 0.f) ? r[k] : expm1f(r[k]);
    const int g = t >> 4;
#pragma unroll
    for (int k = 0; k < 8; ++k) red[g][f0 + k] = r[k];
  }
  __syncthreads();
  if (t == 0) {
    int u = 1;
    for (int i = 1; i < 16; i++) u &= (sB[i] == sB[0]);
    uni = u;
  }
  __syncthreads();
  if (t < 64) {
    const float* rf = &red[0][0];  // row stride 68 floats
    if (uni) {
      float sum = 0.f;
#pragma unroll
      for (int n = 0; n < 16; n++) sum += rf[n * 68 + t];
      atomicAdd(&pool[(size_t)sB[0] * 64 + t], sum);
    } else {
      for (int n = 0; n < 16; n++) {
        atomicAdd(&pool[(size_t)sB[n] * 64 + t], rf[n * 68 + t]);
      }
    }
  }
}

// out[g] = (pool[g,:]/cnt[g]) . Wfc + bfc ; cnt from sorted-batch bounds.
__global__ void final_kernel(const float* __restrict__ pool, const int* __restrict__ gstart,
                             const float* __restrict__ Wfc, const float* __restrict__ bfc,
                             float* __restrict__ out, int G) {
  int wid = (blockIdx.x * blockDim.x + threadIdx.x) >> 6;
  int lane = threadIdx.x & 63;
  if (wid >= G) return;
  float c = (float)max(gstart[wid + 1] - gstart[wid], 1);
  float v = pool[(size_t)wid * 64 + lane] * (1.0f / c) * Wfc[lane];
  v = wave_reduce_sum(v);
  if (lane == 0) out[wid] = v + bfc[0];
}

// ---------------------------------------------------------------------------

extern "C" void kernel_launch(void* const* d_in, const int* in_sizes, int n_in,
                              void* d_out, int out_size, void* d_ws, size_t ws_size,
                              hipStream_t stream) {
  const float* x     = (const float*)d_in[0];
  const int*   ei    = (const int*)d_in[1];
  const int*   batch = (const int*)d_in[2];
  const float* W1    = (const float*)d_in[3];
  const float* asrc1 = (const float*)d_in[4];
  const float* adst1 = (const float*)d_in[5];
  const float* b1    = (const float*)d_in[6];
  const float* W2    = (const float*)d_in[7];
  const float* asrc2 = (const float*)d_in[8];
  const float* adst2 = (const float*)d_in[9];
  const float* b2    = (const float*)d_in[10];
  const float* Wfc   = (const float*)d_in[11];
  const float* bfc   = (const float*)d_in[12];
  float* out = (float*)d_out;

  const int N = in_sizes[0] / 128;  // 100000
  const int E = in_sizes[1] / 2;    // 1600000
  const int G = 256;
  const int M = E + N;              // edges incl self-loops
  const int NB = (N + BIN_NODES - 1) >> BIN_SHIFT;  // 782 bins
  const int NPLACE = (M + PLACE_CHUNK - 1) / PLACE_CHUNK;

  // workspace carve (256B aligned)
  char* p = (char*)d_ws;
  auto alloc = [&](size_t bytes) {
    char* r = p;
    p += (bytes + 255) & ~size_t(255);
    return r;
  };
  unsigned short* hb     = (unsigned short*)alloc((size_t)N * 64 * 2);
  unsigned short* hb2    = (unsigned short*)alloc((size_t)N * 64 * 2);
  float* alsrc  = (float*)alloc((size_t)N * 4);
  float* aldst  = (float*)alloc((size_t)N * 4);
  float* alsrc2 = (float*)alloc((size_t)N * 4);
  float* aldst2 = (float*)alloc((size_t)N * 4);
  int*   rowbeg = (int*)alloc((size_t)N * 4);
  int*   rowend = (int*)alloc((size_t)N * 4);
  int*   csrc   = (int*)alloc((size_t)NB * BIN_CAP * 4);
  unsigned int* binned = (unsigned int*)alloc((size_t)NB * BIN_CAP * 4);
  int*   binCursor = (int*)alloc((size_t)NB * 4);
  float* pool   = (float*)alloc((size_t)G * 64 * 4);
  int*   gstart = (int*)alloc((size_t)(G + 1) * 4);
  unsigned short* w1thi = (unsigned short*)alloc((size_t)64 * 128 * 2);
  unsigned short* w1tlo = (unsigned short*)alloc((size_t)64 * 128 * 2);
  unsigned short* w2thi = (unsigned short*)alloc((size_t)64 * 64 * 2);
  unsigned short* w2tlo = (unsigned short*)alloc((size_t)64 * 64 * 2);

  // ---- stage 1: zero binCursor, then MEGA_A (setup ∪ bin_place) ----
  hipMemsetAsync(binCursor, 0, (size_t)NB * 4, stream);
  mega_a_kernel<<<SETUP_BLOCKS + NPLACE, 256, 0, stream>>>(
      W1, w1thi, w1tlo, W2, w2thi, w2tlo, batch, gstart, pool,
      ei, E, M, NB, binCursor, binned, N, G);

  // ---- stage 2: MEGA_B (finalize ∪ gemm128) ----
  finalize_gemm_kernel<<<NB + (N + 63) / 64, 256, 0, stream>>>(
      binned, binCursor, rowbeg, rowend, csrc, NB,
      x, w1thi, w1tlo, hb, asrc1, adst1, alsrc, aldst, N);

  // ---- layer 1 spmm + layer 2 gemm (fused) ----
  spmm_l1_gemm_kernel<<<N / 16, 256, 0, stream>>>(
      rowbeg, rowend, csrc, alsrc, aldst, hb, b1,
      w2thi, w2tlo, asrc2, adst2, hb2, alsrc2, aldst2, N);

  // ---- layer 2 spmm + pool ----
  spmm_pool_kernel<<<N / 16, 256, 0, stream>>>(
      rowbeg, rowend, csrc, alsrc2, aldst2, hb2, b2, batch, pool, N);

  // ---- readout ----
  final_kernel<<<(G * 64 + 255) / 256, 256, 0, stream>>>(pool, gstart, Wfc, bfc, out, G);
}

// Round 15
// 250.982 us; speedup vs baseline: 1.5679x; 1.0040x over previous
//
#include <hip/hip_runtime.h>
#include <hip/hip_bf16.h>
#include <cstdint>

// ---------------------------------------------------------------------------
// GAT 2-layer model on MI355X.
// R14-R16: spmm gather loop pinned at ~42us: FETCH ~= compulsory per-XCD L2
//   fill of hb (8 x 12.8MB). Hot loop FROZEN.
// R17 (WIN): GEMMs on bf16 MFMA via LDS staging, split precision.
// R18 (REGR): device-wide scatter CSR. Lesson: scatter stays window-confined.
// R19 (REGR): LDS-free gemm. Lesson: barrier-paced staging is load-bearing.
// R20/R24 (WIN): setup fusion; MEGA_A/MEGA_B co-scheduling.
// R21/R22 (REGR): raw per-wave pool atomics. Lesson: block-level pre-reduce.
// R25 (WIN): pool fused into spmm epilogue w/ LDS pre-reduction.
// R26/R27 (WIN 261->252): gemm64 fused into spmm<1> epilogue; W2 loads
//   hoisted; atomic-free al reduction. Budget: ~135us hides in MEGA_A/B.
// R28: (a) gemm128 tile 64->128 rows, MEGA_B at 512 threads: blocks
//   1563->782, sequential barrier-drain rounds per CU ~6->3, W-staging per
//   row halved; finalize reverts to its R20-proven 512t form. Math/K-order
//   identical. (b) expm1f -> __expf()-1 at all ELU sites (hw v_exp_f32;
//   abs err ~1e-7 << 9.8e-4 absmax).
// ---------------------------------------------------------------------------

#define BIN_SHIFT 7
#define BIN_NODES 128
#define BIN_CAP 3584
#define PLACE_CHUNK 2048
#define SETUP_BLOCKS 114  // 32 wsplitW1 + 16 wsplitW2 + 2 bounds + 64 poolzero

typedef __attribute__((ext_vector_type(8))) short bf16x8;
typedef __attribute__((ext_vector_type(4))) float f32x4;

__device__ __forceinline__ float wave_reduce_sum(float v) {
#pragma unroll
  for (int off = 32; off > 0; off >>= 1) v += __shfl_xor(v, off, 64);
  return v;
}

__device__ __forceinline__ unsigned short f2bf(float f) {  // RNE
  unsigned int u = __float_as_uint(f);
  u += 0x7fffu + ((u >> 16) & 1u);
  return (unsigned short)(u >> 16);
}
__device__ __forceinline__ float bf2f(unsigned short u) {
  return __uint_as_float(((unsigned int)u) << 16);
}
__device__ __forceinline__ float elu1(float x) {  // ELU via hw exp
  return (x > 0.f) ? x : (__expf(x) - 1.f);
}

// ---------------- MEGA_A: setup ∪ bin_place ----------------
__global__ __launch_bounds__(256) void mega_a_kernel(
    const float* __restrict__ W1, unsigned short* __restrict__ w1thi,
    unsigned short* __restrict__ w1tlo, const float* __restrict__ W2,
    unsigned short* __restrict__ w2thi, unsigned short* __restrict__ w2tlo,
    const int* __restrict__ batch, int* __restrict__ gstart,
    float* __restrict__ pool, const int* __restrict__ ei, int E, int M,
    int NB, int* __restrict__ binCursor, unsigned int* __restrict__ binned,
    int N, int G) {
  __shared__ int cur[1024];
  __shared__ int res[1024];
  const int b = blockIdx.x;
  const int t = threadIdx.x;

  if (b < 32) {
    int idx = b * 256 + t;  // < 8192 = 128*64
    int n = idx & 63, k = idx >> 6;
    float v = W1[(size_t)k * 64 + n];
    unsigned short h = f2bf(v);
    w1thi[(size_t)n * 128 + k] = h;
    w1tlo[(size_t)n * 128 + k] = f2bf(v - bf2f(h));
    return;
  } else if (b < 48) {
    int idx = (b - 32) * 256 + t;  // < 4096 = 64*64
    int n = idx & 63, k = idx >> 6;
    float v = W2[(size_t)k * 64 + n];
    unsigned short h = f2bf(v);
    w2thi[(size_t)n * 64 + k] = h;
    w2tlo[(size_t)n * 64 + k] = f2bf(v - bf2f(h));
    return;
  } else if (b < 50) {
    int g = (b - 48) * 256 + t;
    if (g <= G) {
      int lo = 0, hi = N;
      while (lo < hi) {
        int mid = (lo + hi) >> 1;
        if (batch[mid] < g) lo = mid + 1;
        else hi = mid;
      }
      gstart[g] = lo;
    }
    return;
  } else if (b < SETUP_BLOCKS) {
    int i = (b - 50) * 256 + t;  // < 16384
    pool[i] = 0.f;
    return;
  }

  // ---- bin_place path ----
  const int cbase = (b - SETUP_BLOCKS) * PLACE_CHUNK;
  for (int i = t; i < NB; i += 256) cur[i] = 0;
  __syncthreads();

  unsigned int pk[PLACE_CHUNK / 256];
  int br[PLACE_CHUNK / 256];
#pragma unroll
  for (int j = 0; j < PLACE_CHUNK / 256; ++j) {
    int i = cbase + t + j * 256;
    if (i < M) {
      int s, d;
      if (i < E) { s = ei[i]; d = ei[E + i]; } else { s = d = i - E; }
      int bb = d >> BIN_SHIFT;
      int r = atomicAdd(&cur[bb], 1);
      pk[j] = ((unsigned int)(d & (BIN_NODES - 1)) << 24) | (unsigned int)s;
      br[j] = (bb << 16) | r;
    } else {
      br[j] = -1;
    }
  }
  __syncthreads();
  for (int i = t; i < NB; i += 256) {
    int c = cur[i];
    res[i] = c ? atomicAdd(&binCursor[i], c) : 0;
  }
  __syncthreads();
#pragma unroll
  for (int j = 0; j < PLACE_CHUNK / 256; ++j) {
    if (br[j] >= 0) {
      int bb = br[j] >> 16;
      int pos = res[bb] + (br[j] & 0xFFFF);
      if (pos < BIN_CAP) binned[(size_t)bb * BIN_CAP + pos] = pk[j];
    }
  }
}

// ---------------- MEGA_B: csr_finalize ∪ gemm128 (512 threads) ------------
// Blocks [0,NB): finalize (R20-proven 512t form, LDS carved from gemm
// arrays); [NB, NB + (N+127)/128): gemm128 with 128-row tiles (8 waves).
__global__ __launch_bounds__(512) void finalize_gemm_kernel(
    const unsigned int* __restrict__ binned, const int* __restrict__ binCursor,
    int* __restrict__ rowbeg, int* __restrict__ rowend, int* __restrict__ csrc,
    int NB,
    const float* __restrict__ A, const unsigned short* __restrict__ Wt_hi,
    const unsigned short* __restrict__ Wt_lo, unsigned short* __restrict__ hb,
    const float* __restrict__ a_src, const float* __restrict__ a_dst,
    float* __restrict__ alsrc, float* __restrict__ aldst, int N) {
  __shared__ unsigned short Ah[128][40], Al[128][40], Bh[64][40], Bl[64][40];
  const int t = threadIdx.x;

  if (blockIdx.x < NB) {
    // ---- finalize path (512t; cnt/wsum carved from Ah/Bh) ----
    int* cnt = (int*)&Ah[0][0];    // 128 ints
    int* wsum = (int*)&Bh[0][0];   // 2 ints
    const int b = blockIdx.x;
    const int nodeBase = b << BIN_SHIFT;
    const int eBase = b * BIN_CAP;
    const int cntE = binCursor[b];

    if (t < 128) cnt[t] = 0;
    __syncthreads();
    for (int i = t; i < cntE; i += 512) {
      atomicAdd(&cnt[binned[eBase + i] >> 24], 1);
    }
    __syncthreads();
    const int lane = t & 63, wv = t >> 6;
    int v = (t < 128) ? cnt[t] : 0;
    int x = v;
#pragma unroll
    for (int o = 1; o < 64; o <<= 1) {
      int u = __shfl_up(x, o, 64);
      if (lane >= o) x += u;
    }
    if (t < 128 && lane == 63) wsum[wv] = x;
    __syncthreads();
    if (t < 128) {
      const int o = ((wv == 1) ? wsum[0] : 0) + x - v;
      int node = nodeBase + t;
      if (node < N) {
        rowbeg[node] = eBase + o;
        rowend[node] = eBase + o + v;
      }
      cnt[t] = o;  // reuse as cursor
    }
    __syncthreads();
    for (int i = t; i < cntE; i += 512) {
      unsigned int pk = binned[eBase + i];
      int r = atomicAdd(&cnt[pk >> 24], 1);
      csrc[eBase + r] = (int)(pk & 0xFFFFFFu);
    }
    return;
  }

  // ---- gemm128 path (R17 math, 128-row tile, 8 waves) ----
  constexpr int KDIM = 128;
  const int block_m = (blockIdx.x - NB) * 128;
  const int lane = t & 63;
  const int m0 = (t >> 6) * 16;       // wave's row base (0..112)
  const int lc = lane & 15;
  const int lr = lane >> 4;
  const int srow = t >> 2;            // staging: A row (0..127)
  const int skslot = (t & 3) * 8;     // staging: k slot (0,8,16,24)

  f32x4 acc[4] = {};

  for (int kc = 0; kc < KDIM; kc += 32) {
    // ---- stage A chunk (128 rows, split fp32 -> bf16 hi/lo) ----
    {
      int gn = block_m + srow;
      if (gn >= N) gn = N - 1;
      const float4 v0 = *(const float4*)(A + (size_t)gn * KDIM + kc + skslot);
      const float4 v1 = *(const float4*)(A + (size_t)gn * KDIM + kc + skslot + 4);
      float v[8] = {v0.x, v0.y, v0.z, v0.w, v1.x, v1.y, v1.z, v1.w};
      unsigned short h8[8], l8[8];
#pragma unroll
      for (int j = 0; j < 8; ++j) {
        h8[j] = f2bf(v[j]);
        l8[j] = f2bf(v[j] - bf2f(h8[j]));
      }
      *(uint4*)&Ah[srow][skslot] = *(const uint4*)h8;
      *(uint4*)&Al[srow][skslot] = *(const uint4*)l8;
    }
    // ---- stage W chunk (64 rows; threads [0,256) only) ----
    if (t < 256) {
      const int wrow = t >> 2;
      const uint4 wh = *(const uint4*)(Wt_hi + (size_t)wrow * KDIM + kc + skslot);
      const uint4 wl = *(const uint4*)(Wt_lo + (size_t)wrow * KDIM + kc + skslot);
      *(uint4*)&Bh[wrow][skslot] = wh;
      *(uint4*)&Bl[wrow][skslot] = wl;
    }
    __syncthreads();

    const bf16x8 ah = *(const bf16x8*)&Ah[m0 + lc][lr * 8];
    const bf16x8 al = *(const bf16x8*)&Al[m0 + lc][lr * 8];
#pragma unroll
    for (int nf = 0; nf < 4; ++nf) {
      const bf16x8 bh = *(const bf16x8*)&Bh[nf * 16 + lc][lr * 8];
      const bf16x8 bl = *(const bf16x8*)&Bl[nf * 16 + lc][lr * 8];
      acc[nf] = __builtin_amdgcn_mfma_f32_16x16x32_bf16(ah, bh, acc[nf], 0, 0, 0);
      acc[nf] = __builtin_amdgcn_mfma_f32_16x16x32_bf16(ah, bl, acc[nf], 0, 0, 0);
      acc[nf] = __builtin_amdgcn_mfma_f32_16x16x32_bf16(al, bh, acc[nf], 0, 0, 0);
    }
    __syncthreads();
  }

  float as4[4], ad4[4];
#pragma unroll
  for (int nf = 0; nf < 4; ++nf) {
    as4[nf] = a_src[nf * 16 + lc];
    ad4[nf] = a_dst[nf * 16 + lc];
  }
#pragma unroll
  for (int r = 0; r < 4; ++r) {
    const int gn = block_m + m0 + lr * 4 + r;
    float ps = 0.f, pd = 0.f;
#pragma unroll
    for (int nf = 0; nf < 4; ++nf) {
      const float v = acc[nf][r];
      if (gn < N) hb[(size_t)gn * 64 + nf * 16 + lc] = f2bf(v);
      ps += v * as4[nf];
      pd += v * ad4[nf];
    }
#pragma unroll
    for (int off = 1; off < 16; off <<= 1) {
      ps += __shfl_xor(ps, off, 64);
      pd += __shfl_xor(pd, off, 64);
    }
    if (lc == 0 && gn < N) {
      alsrc[gn] = ps;
      aldst[gn] = pd;
    }
  }
}

// ---------------- layer 1 spmm + layer 2 gemm (fused, R27 form) ------------
__global__ __launch_bounds__(256) void spmm_l1_gemm_kernel(
    const int* __restrict__ rowbeg, const int* __restrict__ rowend,
    const int* __restrict__ csrc,
    const float* __restrict__ alsrc, const float* __restrict__ aldst,
    const unsigned short* __restrict__ hb, const float* __restrict__ bias,
    const unsigned short* __restrict__ w2thi, const unsigned short* __restrict__ w2tlo,
    const float* __restrict__ a_src2, const float* __restrict__ a_dst2,
    unsigned short* __restrict__ hb2, float* __restrict__ alsrc2,
    float* __restrict__ aldst2, int N) {
  __shared__ unsigned short Hh[16][72], Hl[16][72];
  __shared__ float alp[4][16][2];
  const int t = threadIdx.x;
  const int l = t & 15;        // slot within group
  const int gb = t & 48;       // group base lane within wave
  const int half = l >> 3;     // which edge of the pair this lane serves
  const int f0 = (l & 7) * 8;  // first feature owned by this lane
  const int node = blockIdx.x * 16 + (t >> 4);  // always < N (N%16==0)
  const int start = rowbeg[node];
  const int end = rowend[node];
  const float ad = aldst[node];

  float ssum = 0.f;
  float acc[8] = {};

  int i0 = start + l;
  bool v0 = i0 < end;
  int s = v0 ? csrc[i0] : 0;
  float w;
  {
    float e = alsrc[s] + ad;
    e = (e > 0.f) ? e : 0.2f * e;  // leaky_relu 0.2
    w = v0 ? __expf(fminf(e, 80.f)) : 0.f;
  }

  for (int base = start; base < end; base += 16) {
    int in = base + 16 + l;
    bool vn = in < end;
    int sn = vn ? csrc[in] : 0;
    float aln = alsrc[sn];

    uint4 u[8];
#pragma unroll
    for (int j = 0; j < 8; ++j) {
      int sj = __shfl(s, gb + 2 * j + half, 64);
      u[j] = *(const uint4*)(hb + (size_t)sj * 64 + f0);
    }

    ssum += w;
#pragma unroll
    for (int j = 0; j < 8; ++j) {
      float wj = __shfl(w, gb + 2 * j + half, 64);
      acc[0] += wj * __uint_as_float(u[j].x << 16);
      acc[1] += wj * __uint_as_float(u[j].x & 0xFFFF0000u);
      acc[2] += wj * __uint_as_float(u[j].y << 16);
      acc[3] += wj * __uint_as_float(u[j].y & 0xFFFF0000u);
      acc[4] += wj * __uint_as_float(u[j].z << 16);
      acc[5] += wj * __uint_as_float(u[j].z & 0xFFFF0000u);
      acc[6] += wj * __uint_as_float(u[j].w << 16);
      acc[7] += wj * __uint_as_float(u[j].w & 0xFFFF0000u);
    }

    float en = aln + ad;
    en = (en > 0.f) ? en : 0.2f * en;
    w = vn ? __expf(fminf(en, 80.f)) : 0.f;
    s = sn;
  }

#pragma unroll
  for (int k = 0; k < 8; ++k) acc[k] += __shfl_xor(acc[k], 8, 64);
#pragma unroll
  for (int off = 1; off < 16; off <<= 1) ssum += __shfl_xor(ssum, off, 64);

  // ---- epilogue ----
  // (a) W2 fragment loads FIRST (latency hides under VALU + barrier)
  const int lane = t & 63;
  const int lc2 = lane & 15;
  const int lr2 = lane >> 4;
  const int nf = t >> 6;  // wave owns cols nf*16..nf*16+15
  const size_t boff0 = (size_t)(nf * 16 + lc2) * 64 + lr2 * 8;
  const size_t boff1 = boff0 + 32;
  const bf16x8 bh0 = *(const bf16x8*)(w2thi + boff0);
  const bf16x8 bl0 = *(const bf16x8*)(w2tlo + boff0);
  const bf16x8 bh1 = *(const bf16x8*)(w2thi + boff1);
  const bf16x8 bl1 = *(const bf16x8*)(w2tlo + boff1);
  const float as2 = a_src2[nf * 16 + lc2];
  const float ad2 = a_dst2[nf * 16 + lc2];

  // (b) bias + ELU (h1 row), stage split bf16 into LDS
  if (half == 0) {
    const float inv = 1.0f / ssum;  // >= 1 edge (self-loop)
    float r[8];
#pragma unroll
    for (int k = 0; k < 8; ++k) r[k] = acc[k] * inv;
    const float4 b40 = *(const float4*)(bias + f0);
    const float4 b41 = *(const float4*)(bias + f0 + 4);
    r[0] += b40.x; r[1] += b40.y; r[2] += b40.z; r[3] += b40.w;
    r[4] += b41.x; r[5] += b41.y; r[6] += b41.z; r[7] += b41.w;
#pragma unroll
    for (int k = 0; k < 8; ++k) r[k] = elu1(r[k]);
    unsigned short h8[8], l8[8];
#pragma unroll
    for (int k = 0; k < 8; ++k) {
      h8[k] = f2bf(r[k]);
      l8[k] = f2bf(r[k] - bf2f(h8[k]));
    }
    *(uint4*)&Hh[t >> 4][f0] = *(const uint4*)h8;
    *(uint4*)&Hl[t >> 4][f0] = *(const uint4*)l8;
  }
  __syncthreads();

  // (c) mini-GEMM: h1[16x64] @ W2t[64][64] -> hb2 + al2 (same K-order)
  f32x4 acc2 = {};
  {
    const bf16x8 ah0 = *(const bf16x8*)&Hh[lc2][lr2 * 8];
    const bf16x8 al0 = *(const bf16x8*)&Hl[lc2][lr2 * 8];
    acc2 = __builtin_amdgcn_mfma_f32_16x16x32_bf16(ah0, bh0, acc2, 0, 0, 0);
    acc2 = __builtin_amdgcn_mfma_f32_16x16x32_bf16(ah0, bl0, acc2, 0, 0, 0);
    acc2 = __builtin_amdgcn_mfma_f32_16x16x32_bf16(al0, bh0, acc2, 0, 0, 0);
    const bf16x8 ah1 = *(const bf16x8*)&Hh[lc2][32 + lr2 * 8];
    const bf16x8 al1 = *(const bf16x8*)&Hl[lc2][32 + lr2 * 8];
    acc2 = __builtin_amdgcn_mfma_f32_16x16x32_bf16(ah1, bh1, acc2, 0, 0, 0);
    acc2 = __builtin_amdgcn_mfma_f32_16x16x32_bf16(ah1, bl1, acc2, 0, 0, 0);
    acc2 = __builtin_amdgcn_mfma_f32_16x16x32_bf16(al1, bh1, acc2, 0, 0, 0);
  }

  // (d) hb2 write + atomic-free al reduction (per-wave slots)
  float psl[4], pdl[4];
#pragma unroll
  for (int r = 0; r < 4; ++r) {
    const int nrow = lr2 * 4 + r;
    const int gn = blockIdx.x * 16 + nrow;
    const float v = acc2[r];
    hb2[(size_t)gn * 64 + nf * 16 + lc2] = f2bf(v);
    float ps = v * as2, pd = v * ad2;
#pragma unroll
    for (int off = 1; off < 16; off <<= 1) {
      ps += __shfl_xor(ps, off, 64);
      pd += __shfl_xor(pd, off, 64);
    }
    psl[r] = ps;
    pdl[r] = pd;
  }
  if (lc2 == 0) {
#pragma unroll
    for (int r = 0; r < 4; ++r) {
      alp[nf][lr2 * 4 + r][0] = psl[r];
      alp[nf][lr2 * 4 + r][1] = pdl[r];
    }
  }
  __syncthreads();
  if (t < 16) {
    alsrc2[blockIdx.x * 16 + t] = alp[0][t][0] + alp[1][t][0] + alp[2][t][0] + alp[3][t][0];
    aldst2[blockIdx.x * 16 + t] = alp[0][t][1] + alp[1][t][1] + alp[2][t][1] + alp[3][t][1];
  }
}

// ---------------- layer 2 spmm + pool (R25 proven form) ----------------
__global__ __launch_bounds__(256) void spmm_pool_kernel(
    const int* __restrict__ rowbeg, const int* __restrict__ rowend,
    const int* __restrict__ csrc,
    const float* __restrict__ alsrc, const float* __restrict__ aldst,
    const unsigned short* __restrict__ hb, const float* __restrict__ bias,
    const int* __restrict__ batch, float* __restrict__ pool, int N) {
  __shared__ float red[16][68];
  __shared__ int sB[16];
  __shared__ int uni;
  const int t = threadIdx.x;
  const int l = t & 15;
  const int gb = t & 48;
  const int half = l >> 3;
  const int f0 = (l & 7) * 8;
  const int node = blockIdx.x * 16 + (t >> 4);  // always < N (N%16==0)
  if (t < 16) sB[t] = batch[blockIdx.x * 16 + t];
  const int start = rowbeg[node];
  const int end = rowend[node];
  const float ad = aldst[node];

  float ssum = 0.f;
  float acc[8] = {};

  int i0 = start + l;
  bool v0 = i0 < end;
  int s = v0 ? csrc[i0] : 0;
  float w;
  {
    float e = alsrc[s] + ad;
    e = (e > 0.f) ? e : 0.2f * e;  // leaky_relu 0.2
    w = v0 ? __expf(fminf(e, 80.f)) : 0.f;
  }

  for (int base = start; base < end; base += 16) {
    int in = base + 16 + l;
    bool vn = in < end;
    int sn = vn ? csrc[in] : 0;
    float aln = alsrc[sn];

    uint4 u[8];
#pragma unroll
    for (int j = 0; j < 8; ++j) {
      int sj = __shfl(s, gb + 2 * j + half, 64);
      u[j] = *(const uint4*)(hb + (size_t)sj * 64 + f0);
    }

    ssum += w;
#pragma unroll
    for (int j = 0; j < 8; ++j) {
      float wj = __shfl(w, gb + 2 * j + half, 64);
      acc[0] += wj * __uint_as_float(u[j].x << 16);
      acc[1] += wj * __uint_as_float(u[j].x & 0xFFFF0000u);
      acc[2] += wj * __uint_as_float(u[j].y << 16);
      acc[3] += wj * __uint_as_float(u[j].y & 0xFFFF0000u);
      acc[4] += wj * __uint_as_float(u[j].z << 16);
      acc[5] += wj * __uint_as_float(u[j].z & 0xFFFF0000u);
      acc[6] += wj * __uint_as_float(u[j].w << 16);
      acc[7] += wj * __uint_as_float(u[j].w & 0xFFFF0000u);
    }

    float en = aln + ad;
    en = (en > 0.f) ? en : 0.2f * en;
    w = vn ? __expf(fminf(en, 80.f)) : 0.f;
    s = sn;
  }

#pragma unroll
  for (int k = 0; k < 8; ++k) acc[k] += __shfl_xor(acc[k], 8, 64);
#pragma unroll
  for (int off = 1; off < 16; off <<= 1) ssum += __shfl_xor(ssum, off, 64);

  float r[8];
  if (half == 0) {
    const float inv = 1.0f / ssum;
#pragma unroll
    for (int k = 0; k < 8; ++k) r[k] = acc[k] * inv;
    const float4 b40 = *(const float4*)(bias + f0);
    const float4 b41 = *(const float4*)(bias + f0 + 4);
    r[0] += b40.x; r[1] += b40.y; r[2] += b40.z; r[3] += b40.w;
    r[4] += b41.x; r[5] += b41.y; r[6] += b41.z; r[7] += b41.w;
#pragma unroll
    for (int k = 0; k < 8; ++k) r[k] = elu1(r[k]);
    const int g = t >> 4;
#pragma unroll
    for (int k = 0; k < 8; ++k) red[g][f0 + k] = r[k];
  }
  __syncthreads();
  if (t == 0) {
    int u = 1;
    for (int i = 1; i < 16; i++) u &= (sB[i] == sB[0]);
    uni = u;
  }
  __syncthreads();
  if (t < 64) {
    const float* rf = &red[0][0];  // row stride 68 floats
    if (uni) {
      float sum = 0.f;
#pragma unroll
      for (int n = 0; n < 16; n++) sum += rf[n * 68 + t];
      atomicAdd(&pool[(size_t)sB[0] * 64 + t], sum);
    } else {
      for (int n = 0; n < 16; n++) {
        atomicAdd(&pool[(size_t)sB[n] * 64 + t], rf[n * 68 + t]);
      }
    }
  }
}

// out[g] = (pool[g,:]/cnt[g]) . Wfc + bfc ; cnt from sorted-batch bounds.
__global__ void final_kernel(const float* __restrict__ pool, const int* __restrict__ gstart,
                             const float* __restrict__ Wfc, const float* __restrict__ bfc,
                             float* __restrict__ out, int G) {
  int wid = (blockIdx.x * blockDim.x + threadIdx.x) >> 6;
  int lane = threadIdx.x & 63;
  if (wid >= G) return;
  float c = (float)max(gstart[wid + 1] - gstart[wid], 1);
  float v = pool[(size_t)wid * 64 + lane] * (1.0f / c) * Wfc[lane];
  v = wave_reduce_sum(v);
  if (lane == 0) out[wid] = v + bfc[0];
}

// ---------------------------------------------------------------------------

extern "C" void kernel_launch(void* const* d_in, const int* in_sizes, int n_in,
                              void* d_out, int out_size, void* d_ws, size_t ws_size,
                              hipStream_t stream) {
  const float* x     = (const float*)d_in[0];
  const int*   ei    = (const int*)d_in[1];
  const int*   batch = (const int*)d_in[2];
  const float* W1    = (const float*)d_in[3];
  const float* asrc1 = (const float*)d_in[4];
  const float* adst1 = (const float*)d_in[5];
  const float* b1    = (const float*)d_in[6];
  const float* W2    = (const float*)d_in[7];
  const float* asrc2 = (const float*)d_in[8];
  const float* adst2 = (const float*)d_in[9];
  const float* b2    = (const float*)d_in[10];
  const float* Wfc   = (const float*)d_in[11];
  const float* bfc   = (const float*)d_in[12];
  float* out = (float*)d_out;

  const int N = in_sizes[0] / 128;  // 100000
  const int E = in_sizes[1] / 2;    // 1600000
  const int G = 256;
  const int M = E + N;              // edges incl self-loops
  const int NB = (N + BIN_NODES - 1) >> BIN_SHIFT;  // 782 bins
  const int NPLACE = (M + PLACE_CHUNK - 1) / PLACE_CHUNK;

  // workspace carve (256B aligned)
  char* p = (char*)d_ws;
  auto alloc = [&](size_t bytes) {
    char* r = p;
    p += (bytes + 255) & ~size_t(255);
    return r;
  };
  unsigned short* hb     = (unsigned short*)alloc((size_t)N * 64 * 2);
  unsigned short* hb2    = (unsigned short*)alloc((size_t)N * 64 * 2);
  float* alsrc  = (float*)alloc((size_t)N * 4);
  float* aldst  = (float*)alloc((size_t)N * 4);
  float* alsrc2 = (float*)alloc((size_t)N * 4);
  float* aldst2 = (float*)alloc((size_t)N * 4);
  int*   rowbeg = (int*)alloc((size_t)N * 4);
  int*   rowend = (int*)alloc((size_t)N * 4);
  int*   csrc   = (int*)alloc((size_t)NB * BIN_CAP * 4);
  unsigned int* binned = (unsigned int*)alloc((size_t)NB * BIN_CAP * 4);
  int*   binCursor = (int*)alloc((size_t)NB * 4);
  float* pool   = (float*)alloc((size_t)G * 64 * 4);
  int*   gstart = (int*)alloc((size_t)(G + 1) * 4);
  unsigned short* w1thi = (unsigned short*)alloc((size_t)64 * 128 * 2);
  unsigned short* w1tlo = (unsigned short*)alloc((size_t)64 * 128 * 2);
  unsigned short* w2thi = (unsigned short*)alloc((size_t)64 * 64 * 2);
  unsigned short* w2tlo = (unsigned short*)alloc((size_t)64 * 64 * 2);

  // ---- stage 1: zero binCursor, then MEGA_A (setup ∪ bin_place) ----
  hipMemsetAsync(binCursor, 0, (size_t)NB * 4, stream);
  mega_a_kernel<<<SETUP_BLOCKS + NPLACE, 256, 0, stream>>>(
      W1, w1thi, w1tlo, W2, w2thi, w2tlo, batch, gstart, pool,
      ei, E, M, NB, binCursor, binned, N, G);

  // ---- stage 2: MEGA_B (finalize ∪ gemm128, 512t, 128-row tiles) ----
  finalize_gemm_kernel<<<NB + (N + 127) / 128, 512, 0, stream>>>(
      binned, binCursor, rowbeg, rowend, csrc, NB,
      x, w1thi, w1tlo, hb, asrc1, adst1, alsrc, aldst, N);

  // ---- layer 1 spmm + layer 2 gemm (fused) ----
  spmm_l1_gemm_kernel<<<N / 16, 256, 0, stream>>>(
      rowbeg, rowend, csrc, alsrc, aldst, hb, b1,
      w2thi, w2tlo, asrc2, adst2, hb2, alsrc2, aldst2, N);

  // ---- layer 2 spmm + pool ----
  spmm_pool_kernel<<<N / 16, 256, 0, stream>>>(
      rowbeg, rowend, csrc, alsrc2, aldst2, hb2, b2, batch, pool, N);

  // ---- readout ----
  final_kernel<<<(G * 64 + 255) / 256, 256, 0, stream>>>(pool, gstart, Wfc, bfc, out, G);
}